// Round 1
// baseline (246.329 us; speedup 1.0000x reference)
//
#include <hip/hip_runtime.h>

// Problem constants: B=2, N=2048, C=1024, H=16, hd=64
// x:(2,2048,1024) f32; Wqkv:(1024,3072); Wproj:(1024,1024); bproj:(1024); q_scale,k_scale:(64)
// out:(2,2048,1024) f32

typedef _Float16 half_t;
typedef __attribute__((ext_vector_type(4))) _Float16 half4v;
typedef __attribute__((ext_vector_type(8))) _Float16 half8;
typedef __attribute__((ext_vector_type(8))) short bf16x8;
typedef __attribute__((ext_vector_type(4))) float f32x4;

#define DI __device__ __forceinline__

DI unsigned short f2bf(float f) {
    unsigned u = __float_as_uint(f);
    u += 0x7fff + ((u >> 16) & 1);   // round-to-nearest-even
    return (unsigned short)(u >> 16);
}
DI float bf2f(unsigned short h) { return __uint_as_float(((unsigned)h) << 16); }

DI void gl_lds16(const void* g, void* l) {
    __builtin_amdgcn_global_load_lds((const __attribute__((address_space(1))) void*)g,
                                     (__attribute__((address_space(3))) void*)l, 16, 0, 0);
}

// ---------------- prep kernels ----------------

// x f32 -> bf16 hi/lo split
__global__ void prep_x(const float* __restrict__ x, unsigned short* __restrict__ xhi,
                       unsigned short* __restrict__ xlo, int n) {
    int i = (blockIdx.x * 256 + threadIdx.x) * 4;
    if (i >= n) return;
    float4 v = *(const float4*)(x + i);
    float f[4] = {v.x, v.y, v.z, v.w};
    unsigned short h[4], lo[4];
#pragma unroll
    for (int e = 0; e < 4; e++) {
        h[e] = f2bf(f[e]);
        lo[e] = f2bf(f[e] - bf2f(h[e]));
    }
    *(ushort4*)(xhi + i) = ushort4{h[0], h[1], h[2], h[3]};
    *(ushort4*)(xlo + i) = ushort4{lo[0], lo[1], lo[2], lo[3]};
}

// Wqkv (1024 x 3072) f32 -> transposed bf16 hi/lo (3072 x 1024)
__global__ void prep_wqkv(const float* __restrict__ w, unsigned short* __restrict__ whit,
                          unsigned short* __restrict__ wlot) {
    __shared__ float t[32][33];
    int c0 = blockIdx.x * 32, r0 = blockIdx.y * 32;
    int tx = threadIdx.x, ty = threadIdx.y; // 32x8
#pragma unroll
    for (int i = 0; i < 4; i++)
        t[ty + 8 * i][tx] = w[(size_t)(r0 + ty + 8 * i) * 3072 + c0 + tx];
    __syncthreads();
#pragma unroll
    for (int i = 0; i < 4; i++) {
        float f = t[tx][ty + 8 * i];
        unsigned short h = f2bf(f);
        unsigned short l = f2bf(f - bf2f(h));
        size_t o = (size_t)(c0 + ty + 8 * i) * 1024 + r0 + tx;
        whit[o] = h;
        wlot[o] = l;
    }
}

// Wproj (1024 x 1024) f32 -> transposed fp16 (1024 x 1024)
__global__ void prep_wproj(const float* __restrict__ w, half_t* __restrict__ wt) {
    __shared__ float t[32][33];
    int c0 = blockIdx.x * 32, r0 = blockIdx.y * 32;
    int tx = threadIdx.x, ty = threadIdx.y;
#pragma unroll
    for (int i = 0; i < 4; i++)
        t[ty + 8 * i][tx] = w[(size_t)(r0 + ty + 8 * i) * 1024 + c0 + tx];
    __syncthreads();
#pragma unroll
    for (int i = 0; i < 4; i++)
        wt[(size_t)(c0 + ty + 8 * i) * 1024 + r0 + tx] = (half_t)t[tx][ty + 8 * i];
}

// ---------------- QKV GEMM: bf16 3-term split (hi*hi + hi*lo + lo*hi) ----------------
// C[4096][3072] = x[4096][1024] @ Wqkv ; A row-major M x K, B given transposed N x K.
// 128x128 tile, BK=32, LDS rows pack [hi(4 chunks)|lo(4 chunks)] = 128B, XOR chunk swizzle.
// Epilogue scatters to q/k (b,h,n,f) fp16 and v transposed (b,h,f,n) fp16.
__global__ __launch_bounds__(256) void gemm_qkv(
    const unsigned short* __restrict__ xhi, const unsigned short* __restrict__ xlo,
    const unsigned short* __restrict__ whit, const unsigned short* __restrict__ wlot,
    half_t* __restrict__ qh, half_t* __restrict__ kh, half_t* __restrict__ vth) {
    const int K = 1024;
    __shared__ __align__(16) unsigned short Al[128 * 64];
    __shared__ __align__(16) unsigned short Bl[128 * 64];
    int tid = threadIdx.x;
    int w = tid >> 6, l = tid & 63;
    int wr = w >> 1, wc = w & 1;
    int g = l >> 4, r = l & 15;
    int m0 = blockIdx.x * 128, n0 = blockIdx.y * 128;
    f32x4 acc[4][4] = {};

    for (int k0 = 0; k0 < K; k0 += 32) {
#pragma unroll
        for (int p = 0; p < 4; p++) {
            int ci = (p * 4 + w) * 64 + l;
            int row = ci >> 3, c = ci & 7;
            int lc = c ^ (row & 7); // logical chunk that must land at phys chunk c
            const unsigned short* sa = (lc < 4)
                ? (xhi + (size_t)(m0 + row) * K + k0 + lc * 8)
                : (xlo + (size_t)(m0 + row) * K + k0 + (lc - 4) * 8);
            gl_lds16(sa, Al + (p * 4 + w) * 512);
            const unsigned short* sb = (lc < 4)
                ? (whit + (size_t)(n0 + row) * K + k0 + lc * 8)
                : (wlot + (size_t)(n0 + row) * K + k0 + (lc - 4) * 8);
            gl_lds16(sb, Bl + (p * 4 + w) * 512);
        }
        __syncthreads();

        bf16x8 ahi[4], alo[4], bhi[4], blo[4];
#pragma unroll
        for (int i = 0; i < 4; i++) {
            int row = wr * 64 + i * 16 + r;
            ahi[i] = *(const bf16x8*)(Al + row * 64 + ((g ^ (row & 7)) << 3));
            alo[i] = *(const bf16x8*)(Al + row * 64 + (((4 + g) ^ (row & 7)) << 3));
            int rowb = wc * 64 + i * 16 + r;
            bhi[i] = *(const bf16x8*)(Bl + rowb * 64 + ((g ^ (rowb & 7)) << 3));
            blo[i] = *(const bf16x8*)(Bl + rowb * 64 + (((4 + g) ^ (rowb & 7)) << 3));
        }
#pragma unroll
        for (int i = 0; i < 4; i++)
#pragma unroll
            for (int j = 0; j < 4; j++) {
                acc[i][j] = __builtin_amdgcn_mfma_f32_16x16x32_bf16(ahi[i], bhi[j], acc[i][j], 0, 0, 0);
                acc[i][j] = __builtin_amdgcn_mfma_f32_16x16x32_bf16(ahi[i], blo[j], acc[i][j], 0, 0, 0);
                acc[i][j] = __builtin_amdgcn_mfma_f32_16x16x32_bf16(alo[i], bhi[j], acc[i][j], 0, 0, 0);
            }
        __syncthreads();
    }

    // epilogue: D mapping col=l&15, row=(l>>4)*4+reg
#pragma unroll
    for (int i = 0; i < 4; i++)
#pragma unroll
        for (int j = 0; j < 4; j++) {
            int gcol = n0 + wc * 64 + j * 16 + r;
            int t = gcol >> 10;
            int h = (gcol >> 6) & 15;
            int f = gcol & 63;
            int growb = m0 + wr * 64 + i * 16 + g * 4;
            int b = growb >> 11;
            int n = growb & 2047;
            int bh = b * 16 + h;
            if (t == 2) {
                half4v pv;
#pragma unroll
                for (int rr = 0; rr < 4; rr++) pv[rr] = (half_t)acc[i][j][rr];
                *(half4v*)(vth + ((size_t)bh * 64 + f) * 2048 + n) = pv;
            } else {
                half_t* dst = (t == 0 ? qh : kh);
#pragma unroll
                for (int rr = 0; rr < 4; rr++)
                    dst[((size_t)bh * 2048 + n + rr) * 64 + f] = (half_t)acc[i][j][rr];
            }
        }
}

// ---------------- RMSNorm on q,k (in place, fp16), folds 1/sqrt(hd) into q ----------------
__global__ void rmsnorm_qk(half_t* __restrict__ qh, half_t* __restrict__ kh,
                           const float* __restrict__ qs, const float* __restrict__ ks2) {
    int tid = blockIdx.x * 256 + threadIdx.x;
    int row = tid >> 4;  // 0..131071 : first 65536 rows = q, rest = k
    int lq = tid & 15;
    bool isq = row < 65536;
    half_t* base = isq ? (qh + (size_t)row * 64) : (kh + (size_t)(row - 65536) * 64);
    const float* sc = isq ? qs : ks2;
    float extra = isq ? 0.125f : 1.0f;  // fold hd^-0.5 logit scale into q
    half4v v = *(half4v*)(base + lq * 4);
    float f0 = (float)v[0], f1 = (float)v[1], f2 = (float)v[2], f3 = (float)v[3];
    float ss = f0 * f0 + f1 * f1 + f2 * f2 + f3 * f3;
#pragma unroll
    for (int d = 1; d < 16; d <<= 1) ss += __shfl_xor(ss, d, 64);
    float rms = sqrtf(ss) * 0.125f;  // ||x|| / sqrt(64)
    float inv = extra / (rms + 1e-8f);
    half4v o;
    o[0] = (half_t)(f0 * sc[lq * 4 + 0] * inv);
    o[1] = (half_t)(f1 * sc[lq * 4 + 1] * inv);
    o[2] = (half_t)(f2 * sc[lq * 4 + 2] * inv);
    o[3] = (half_t)(f3 * sc[lq * 4 + 3] * inv);
    *(half4v*)(base + lq * 4) = o;
}

// ---------------- flash attention (fp16 MFMA), q pre-scaled ----------------
// grid (32 q-tiles, 32 bh). Block: 256 thr = 4 waves, each wave 16 q-rows.
__global__ __launch_bounds__(256) void attn(
    const half_t* __restrict__ qh, const half_t* __restrict__ kh,
    const half_t* __restrict__ vth, half_t* __restrict__ aoh) {
    int bh = blockIdx.y;
    int q0 = blockIdx.x * 64;
    const half_t* Qp = qh + (size_t)bh * 2048 * 64;
    const half_t* Kp = kh + (size_t)bh * 2048 * 64;
    const half_t* Vp = vth + (size_t)bh * 64 * 2048;  // (feat, n)
    __shared__ __align__(16) half_t Kl[64 * 64];
    __shared__ __align__(16) half_t Vl[64 * 64];   // [feat][kv]
    __shared__ __align__(16) half_t Pl[4][16 * 64];
    int tid = threadIdx.x, w = tid >> 6, l = tid & 63, g = l >> 4, r = l & 15;

    half8 qf[2];
#pragma unroll
    for (int ks = 0; ks < 2; ks++)
        qf[ks] = *(const half8*)(Qp + (size_t)(q0 + w * 16 + r) * 64 + ks * 32 + g * 8);

    f32x4 o[4] = {};
    float mrow[4], lsum[4];
#pragma unroll
    for (int rr = 0; rr < 4; rr++) { mrow[rr] = -1e30f; lsum[rr] = 0.f; }

    for (int t = 0; t < 32; t++) {
        int kv0 = t * 64;
#pragma unroll
        for (int p = 0; p < 2; p++) {
            int ci = (p * 4 + w) * 64 + l;
            int row = ci >> 3, c = ci & 7;
            int lc = c ^ (row & 7);
            gl_lds16(Kp + (size_t)(kv0 + row) * 64 + lc * 8, Kl + (p * 4 + w) * 512);
            gl_lds16(Vp + (size_t)row * 2048 + kv0 + lc * 8, Vl + (p * 4 + w) * 512);
        }
        __syncthreads();

        // S = Q K^T (q already has the 0.125 scale)
        f32x4 s[4] = {};
#pragma unroll
        for (int ks = 0; ks < 2; ks++)
#pragma unroll
            for (int j = 0; j < 4; j++) {
                int row = j * 16 + r;
                half8 kf = *(const half8*)(Kl + row * 64 + (((4 * ks + g) ^ (row & 7)) << 3));
                s[j] = __builtin_amdgcn_mfma_f32_16x16x32_f16(qf[ks], kf, s[j], 0, 0, 0);
            }

        // online softmax; lane holds rows g*4+rr, col j*16+r
#pragma unroll
        for (int rr = 0; rr < 4; rr++) {
            float mx = fmaxf(fmaxf(s[0][rr], s[1][rr]), fmaxf(s[2][rr], s[3][rr]));
#pragma unroll
            for (int d = 1; d < 16; d <<= 1) mx = fmaxf(mx, __shfl_xor(mx, d, 64));
            float mn = fmaxf(mrow[rr], mx);
            float fac = __expf(mrow[rr] - mn);
            float rs = 0.f;
#pragma unroll
            for (int j2 = 0; j2 < 4; j2++) {
                float p = __expf(s[j2][rr] - mn);
                s[j2][rr] = p;
                rs += p;
            }
#pragma unroll
            for (int d = 1; d < 16; d <<= 1) rs += __shfl_xor(rs, d, 64);
            lsum[rr] = lsum[rr] * fac + rs;
            mrow[rr] = mn;
#pragma unroll
            for (int cf = 0; cf < 4; cf++) o[cf][rr] *= fac;
            int lr = g * 4 + rr;
#pragma unroll
            for (int j2 = 0; j2 < 4; j2++) {
                int col = j2 * 16 + r;
                int ch = col >> 3;
                Pl[w][lr * 64 + ((ch ^ (lr & 7)) << 3) + (col & 7)] = (half_t)s[j2][rr];
            }
        }

        // O += P V
#pragma unroll
        for (int ks = 0; ks < 2; ks++) {
            half8 pf = *(const half8*)(Pl[w] + r * 64 + (((4 * ks + g) ^ (r & 7)) << 3));
#pragma unroll
            for (int cf = 0; cf < 4; cf++) {
                int row = cf * 16 + r;
                half8 vf = *(const half8*)(Vl + row * 64 + (((4 * ks + g) ^ (row & 7)) << 3));
                o[cf] = __builtin_amdgcn_mfma_f32_16x16x32_f16(pf, vf, o[cf], 0, 0, 0);
            }
        }
        __syncthreads();
    }

    int b = bh >> 4, h = bh & 15;
#pragma unroll
    for (int rr = 0; rr < 4; rr++) {
        float inv = 1.0f / lsum[rr];
        int n = q0 + w * 16 + g * 4 + rr;
#pragma unroll
        for (int cf = 0; cf < 4; cf++)
            aoh[((size_t)b * 2048 + n) * 1024 + h * 64 + cf * 16 + r] = (half_t)(o[cf][rr] * inv);
    }
}

// ---------------- proj GEMM: fp16, BK=64, + bias, f32 out ----------------
__global__ __launch_bounds__(256) void gemm_proj(
    const half_t* __restrict__ A, const half_t* __restrict__ Bt,
    const float* __restrict__ bias, float* __restrict__ out) {
    const int K = 1024;
    __shared__ __align__(16) half_t Al[128 * 64];
    __shared__ __align__(16) half_t Bl[128 * 64];
    int tid = threadIdx.x, w = tid >> 6, l = tid & 63;
    int wr = w >> 1, wc = w & 1, g = l >> 4, r = l & 15;
    int m0 = blockIdx.x * 128, n0 = blockIdx.y * 128;
    f32x4 acc[4][4] = {};

    for (int k0 = 0; k0 < K; k0 += 64) {
#pragma unroll
        for (int p = 0; p < 4; p++) {
            int ci = (p * 4 + w) * 64 + l;
            int row = ci >> 3, c = ci & 7;
            int lc = c ^ (row & 7);
            gl_lds16(A + (size_t)(m0 + row) * K + k0 + lc * 8, Al + (p * 4 + w) * 512);
            gl_lds16(Bt + (size_t)(n0 + row) * K + k0 + lc * 8, Bl + (p * 4 + w) * 512);
        }
        __syncthreads();
#pragma unroll
        for (int ks = 0; ks < 2; ks++) {
            half8 af[4], bf[4];
#pragma unroll
            for (int i = 0; i < 4; i++) {
                int row = wr * 64 + i * 16 + r;
                af[i] = *(const half8*)(Al + row * 64 + (((4 * ks + g) ^ (row & 7)) << 3));
                int rowb = wc * 64 + i * 16 + r;
                bf[i] = *(const half8*)(Bl + rowb * 64 + (((4 * ks + g) ^ (rowb & 7)) << 3));
            }
#pragma unroll
            for (int i = 0; i < 4; i++)
#pragma unroll
                for (int j = 0; j < 4; j++)
                    acc[i][j] = __builtin_amdgcn_mfma_f32_16x16x32_f16(af[i], bf[j], acc[i][j], 0, 0, 0);
        }
        __syncthreads();
    }

#pragma unroll
    for (int i = 0; i < 4; i++)
#pragma unroll
        for (int j = 0; j < 4; j++) {
            int gcol = n0 + wc * 64 + j * 16 + r;
            float bv = bias[gcol];
#pragma unroll
            for (int rr = 0; rr < 4; rr++) {
                int grow = m0 + wr * 64 + i * 16 + g * 4 + rr;
                out[(size_t)grow * 1024 + gcol] = acc[i][j][rr] + bv;
            }
        }
}

// ---------------- launch ----------------
extern "C" void kernel_launch(void* const* d_in, const int* in_sizes, int n_in,
                              void* d_out, int out_size, void* d_ws, size_t ws_size,
                              hipStream_t stream) {
    const float* x = (const float*)d_in[0];
    const float* Wqkv = (const float*)d_in[1];
    const float* Wproj = (const float*)d_in[2];
    const float* bproj = (const float*)d_in[3];
    const float* qscale = (const float*)d_in[4];
    const float* kscale = (const float*)d_in[5];
    float* out = (float*)d_out;

    char* ws = (char*)d_ws;
    unsigned short* xhi = (unsigned short*)(ws + 0);          //  8.0 MB
    unsigned short* xlo = (unsigned short*)(ws + 8388608);    //  8.0 MB
    unsigned short* whit = (unsigned short*)(ws + 16777216);  //  6.0 MB
    unsigned short* wlot = (unsigned short*)(ws + 23068672);  //  6.0 MB
    half_t* wpt = (half_t*)(ws + 29360128);                   //  2.0 MB
    half_t* qh = (half_t*)(ws + 31457280);                    //  8.0 MB (b,h,n,f)
    half_t* kh = (half_t*)(ws + 39845888);                    //  8.0 MB (b,h,n,f)
    half_t* vth = (half_t*)(ws + 48234496);                   //  8.0 MB (b,h,f,n)
    half_t* aoh = (half_t*)(ws + 56623104);                   //  8.0 MB (b,n,c)

    prep_x<<<4096, 256, 0, stream>>>(x, xhi, xlo, 4194304);
    prep_wqkv<<<dim3(96, 32), dim3(32, 8), 0, stream>>>(Wqkv, whit, wlot);
    prep_wproj<<<dim3(32, 32), dim3(32, 8), 0, stream>>>(Wproj, wpt);
    gemm_qkv<<<dim3(32, 24), 256, 0, stream>>>(xhi, xlo, whit, wlot, qh, kh, vth);
    rmsnorm_qk<<<8192, 256, 0, stream>>>(qh, kh, qscale, kscale);
    attn<<<dim3(32, 32), 256, 0, stream>>>(qh, kh, vth, aoh);
    gemm_proj<<<dim3(32, 8), 256, 0, stream>>>(aoh, wpt, bproj, out);
}

// Round 3
// 194.844 us; speedup vs baseline: 1.2642x; 1.2642x over previous
//
#include <hip/hip_runtime.h>

// Problem constants: B=2, N=2048, C=1024, H=16, hd=64
// x:(2,2048,1024) f32; Wqkv:(1024,3072); Wproj:(1024,1024); bproj:(1024); q_scale,k_scale:(64)
// out:(2,2048,1024) f32

typedef _Float16 half_t;
typedef __attribute__((ext_vector_type(2))) __fp16 fp16x2;
typedef __attribute__((ext_vector_type(4))) _Float16 half4v;
typedef __attribute__((ext_vector_type(8))) _Float16 half8;
typedef __attribute__((ext_vector_type(8))) short bf16x8;
typedef __attribute__((ext_vector_type(4))) float f32x4;

#define DI __device__ __forceinline__

DI unsigned short f2bf(float f) {
    unsigned u = __float_as_uint(f);
    u += 0x7fff + ((u >> 16) & 1);   // round-to-nearest-even
    return (unsigned short)(u >> 16);
}
DI float bf2f(unsigned short h) { return __uint_as_float(((unsigned)h) << 16); }

DI void gl_lds16(const void* g, void* l) {
    __builtin_amdgcn_global_load_lds((const __attribute__((address_space(1))) void*)g,
                                     (__attribute__((address_space(3))) void*)l, 16, 0, 0);
}

DI float exp2_fast(float x) {
    float r;
    asm("v_exp_f32 %0, %1" : "=v"(r) : "v"(x));
    return r;
}

// ---------------- prep kernels ----------------

// x f32 -> bf16 hi/lo split
__global__ void prep_x(const float* __restrict__ x, unsigned short* __restrict__ xhi,
                       unsigned short* __restrict__ xlo, int n) {
    int i = (blockIdx.x * 256 + threadIdx.x) * 4;
    if (i >= n) return;
    float4 v = *(const float4*)(x + i);
    float f[4] = {v.x, v.y, v.z, v.w};
    unsigned short h[4], lo[4];
#pragma unroll
    for (int e = 0; e < 4; e++) {
        h[e] = f2bf(f[e]);
        lo[e] = f2bf(f[e] - bf2f(h[e]));
    }
    *(ushort4*)(xhi + i) = ushort4{h[0], h[1], h[2], h[3]};
    *(ushort4*)(xlo + i) = ushort4{lo[0], lo[1], lo[2], lo[3]};
}

// Wqkv (1024 x 3072) f32 -> transposed bf16 hi/lo (3072 x 1024)
__global__ void prep_wqkv(const float* __restrict__ w, unsigned short* __restrict__ whit,
                          unsigned short* __restrict__ wlot) {
    __shared__ float t[32][33];
    int c0 = blockIdx.x * 32, r0 = blockIdx.y * 32;
    int tx = threadIdx.x, ty = threadIdx.y; // 32x8
#pragma unroll
    for (int i = 0; i < 4; i++)
        t[ty + 8 * i][tx] = w[(size_t)(r0 + ty + 8 * i) * 3072 + c0 + tx];
    __syncthreads();
#pragma unroll
    for (int i = 0; i < 4; i++) {
        float f = t[tx][ty + 8 * i];
        unsigned short h = f2bf(f);
        unsigned short l = f2bf(f - bf2f(h));
        size_t o = (size_t)(c0 + ty + 8 * i) * 1024 + r0 + tx;
        whit[o] = h;
        wlot[o] = l;
    }
}

// Wproj (1024 x 1024) f32 -> transposed fp16 (1024 x 1024)
__global__ void prep_wproj(const float* __restrict__ w, half_t* __restrict__ wt) {
    __shared__ float t[32][33];
    int c0 = blockIdx.x * 32, r0 = blockIdx.y * 32;
    int tx = threadIdx.x, ty = threadIdx.y;
#pragma unroll
    for (int i = 0; i < 4; i++)
        t[ty + 8 * i][tx] = w[(size_t)(r0 + ty + 8 * i) * 1024 + c0 + tx];
    __syncthreads();
#pragma unroll
    for (int i = 0; i < 4; i++)
        wt[(size_t)(c0 + ty + 8 * i) * 1024 + r0 + tx] = (half_t)t[tx][ty + 8 * i];
}

// ---------------- QKV GEMM: bf16 3-term split (hi*hi + hi*lo + lo*hi) ----------------
__global__ __launch_bounds__(256) void gemm_qkv(
    const unsigned short* __restrict__ xhi, const unsigned short* __restrict__ xlo,
    const unsigned short* __restrict__ whit, const unsigned short* __restrict__ wlot,
    half_t* __restrict__ qh, half_t* __restrict__ kh, half_t* __restrict__ vth) {
    const int K = 1024;
    __shared__ __align__(16) unsigned short Al[128 * 64];
    __shared__ __align__(16) unsigned short Bl[128 * 64];
    int tid = threadIdx.x;
    int w = tid >> 6, l = tid & 63;
    int wr = w >> 1, wc = w & 1;
    int g = l >> 4, r = l & 15;
    int m0 = blockIdx.x * 128, n0 = blockIdx.y * 128;
    f32x4 acc[4][4] = {};

    for (int k0 = 0; k0 < K; k0 += 32) {
#pragma unroll
        for (int p = 0; p < 4; p++) {
            int ci = (p * 4 + w) * 64 + l;
            int row = ci >> 3, c = ci & 7;
            int lc = c ^ (row & 7); // logical chunk that must land at phys chunk c
            const unsigned short* sa = (lc < 4)
                ? (xhi + (size_t)(m0 + row) * K + k0 + lc * 8)
                : (xlo + (size_t)(m0 + row) * K + k0 + (lc - 4) * 8);
            gl_lds16(sa, Al + (p * 4 + w) * 512);
            const unsigned short* sb = (lc < 4)
                ? (whit + (size_t)(n0 + row) * K + k0 + lc * 8)
                : (wlot + (size_t)(n0 + row) * K + k0 + (lc - 4) * 8);
            gl_lds16(sb, Bl + (p * 4 + w) * 512);
        }
        __syncthreads();

        bf16x8 ahi[4], alo[4], bhi[4], blo[4];
#pragma unroll
        for (int i = 0; i < 4; i++) {
            int row = wr * 64 + i * 16 + r;
            ahi[i] = *(const bf16x8*)(Al + row * 64 + ((g ^ (row & 7)) << 3));
            alo[i] = *(const bf16x8*)(Al + row * 64 + (((4 + g) ^ (row & 7)) << 3));
            int rowb = wc * 64 + i * 16 + r;
            bhi[i] = *(const bf16x8*)(Bl + rowb * 64 + ((g ^ (rowb & 7)) << 3));
            blo[i] = *(const bf16x8*)(Bl + rowb * 64 + (((4 + g) ^ (rowb & 7)) << 3));
        }
#pragma unroll
        for (int i = 0; i < 4; i++)
#pragma unroll
            for (int j = 0; j < 4; j++) {
                acc[i][j] = __builtin_amdgcn_mfma_f32_16x16x32_bf16(ahi[i], bhi[j], acc[i][j], 0, 0, 0);
                acc[i][j] = __builtin_amdgcn_mfma_f32_16x16x32_bf16(ahi[i], blo[j], acc[i][j], 0, 0, 0);
                acc[i][j] = __builtin_amdgcn_mfma_f32_16x16x32_bf16(alo[i], bhi[j], acc[i][j], 0, 0, 0);
            }
        __syncthreads();
    }

    // epilogue: D mapping col=l&15, row=(l>>4)*4+reg
#pragma unroll
    for (int i = 0; i < 4; i++)
#pragma unroll
        for (int j = 0; j < 4; j++) {
            int gcol = n0 + wc * 64 + j * 16 + r;
            int t = gcol >> 10;
            int h = (gcol >> 6) & 15;
            int f = gcol & 63;
            int growb = m0 + wr * 64 + i * 16 + g * 4;
            int b = growb >> 11;
            int n = growb & 2047;
            int bh = b * 16 + h;
            if (t == 2) {
                half4v pv;
#pragma unroll
                for (int rr = 0; rr < 4; rr++) pv[rr] = (half_t)acc[i][j][rr];
                *(half4v*)(vth + ((size_t)bh * 64 + f) * 2048 + n) = pv;
            } else {
                half_t* dst = (t == 0 ? qh : kh);
#pragma unroll
                for (int rr = 0; rr < 4; rr++)
                    dst[((size_t)bh * 2048 + n + rr) * 64 + f] = (half_t)acc[i][j][rr];
            }
        }
}

// ---------------- RMSNorm on q,k (in place, fp16) ----------------
// folds (hd^-0.5 * log2e) into q so attention logits are in log2 units
__global__ void rmsnorm_qk(half_t* __restrict__ qh, half_t* __restrict__ kh,
                           const float* __restrict__ qs, const float* __restrict__ ks2) {
    int tid = blockIdx.x * 256 + threadIdx.x;
    int row = tid >> 4;  // 0..131071 : first 65536 rows = q, rest = k
    int lq = tid & 15;
    bool isq = row < 65536;
    half_t* base = isq ? (qh + (size_t)row * 64) : (kh + (size_t)(row - 65536) * 64);
    const float* sc = isq ? qs : ks2;
    float extra = isq ? (0.125f * 1.44269504f) : 1.0f;
    half4v v = *(half4v*)(base + lq * 4);
    float f0 = (float)v[0], f1 = (float)v[1], f2 = (float)v[2], f3 = (float)v[3];
    float ss = f0 * f0 + f1 * f1 + f2 * f2 + f3 * f3;
#pragma unroll
    for (int d = 1; d < 16; d <<= 1) ss += __shfl_xor(ss, d, 64);
    float rms = sqrtf(ss) * 0.125f;  // ||x|| / sqrt(64)
    float inv = extra / (rms + 1e-8f);
    half4v o;
    o[0] = (half_t)(f0 * sc[lq * 4 + 0] * inv);
    o[1] = (half_t)(f1 * sc[lq * 4 + 1] * inv);
    o[2] = (half_t)(f2 * sc[lq * 4 + 2] * inv);
    o[3] = (half_t)(f3 * sc[lq * 4 + 3] * inv);
    *(half4v*)(base + lq * 4) = o;
}

// ---------------- flash attention, swapped-QK in-register softmax ----------------
// grid (16 q-tiles, 32 bh). Block: 512 thr = 8 waves, each wave 16 q-rows (1 q/lane).
// S^T = mfma(K_frag, Q_frag): lane holds S^T[kv=16t+4g+reg][q=r].
// PV as O^T = mfma(V^T_frag, P^T_frag); P repacked via per-wave swizzled LDS.
__global__ __launch_bounds__(512) void attn(
    const half_t* __restrict__ qh, const half_t* __restrict__ kh,
    const half_t* __restrict__ vth, half_t* __restrict__ aoh) {
    int bh = blockIdx.y;
    int q0 = blockIdx.x * 128;
    const half_t* Qp = qh + (size_t)bh * 2048 * 64;
    const half_t* Kp = kh + (size_t)bh * 2048 * 64;
    const half_t* Vp = vth + (size_t)bh * 64 * 2048;  // (feat, n)
    __shared__ __align__(16) half_t Kl[2][64 * 64];
    __shared__ __align__(16) half_t Vl[2][64 * 64];   // [feat][kv]
    __shared__ __align__(16) half_t Pl[8][16 * 64];   // per-wave: 16 q x 64 kv (chunk-swizzled)
    int tid = threadIdx.x, w = tid >> 6, l = tid & 63, g = l >> 4, r = l & 15;

    // staging coords: 512 chunks of 16B per 64x64 fp16 buffer, 1 K-chunk + 1 V-chunk per thread
    int srow = tid >> 3, sc = tid & 7, slc = sc ^ (srow & 7);

    // Q fragment: Q[q=r][hd = 32ks + 8g + e]  (serves as B-operand of swapped QK^T)
    half8 qf[2];
#pragma unroll
    for (int ks = 0; ks < 2; ks++)
        qf[ks] = *(const half8*)(Qp + (size_t)(q0 + w * 16 + r) * 64 + ks * 32 + g * 8);

    f32x4 o[4] = {};          // O^T[d = 16cf + 4g + reg][q = r]
    float m = -1e30f, lsum = 0.f;

    // prologue: stage tile 0
    gl_lds16(Kp + (size_t)srow * 64 + slc * 8, &Kl[0][0] + tid * 8);
    gl_lds16(Vp + (size_t)srow * 2048 + slc * 8, &Vl[0][0] + tid * 8);
    __syncthreads();

    int cur = 0;
    for (int t = 0; t < 32; t++) {
        if (t < 31) {
            int kv1 = (t + 1) * 64;
            gl_lds16(Kp + (size_t)(kv1 + srow) * 64 + slc * 8, &Kl[cur ^ 1][0] + tid * 8);
            gl_lds16(Vp + (size_t)srow * 2048 + kv1 + slc * 8, &Vl[cur ^ 1][0] + tid * 8);
        }
        const half_t* Kc = &Kl[cur][0];
        const half_t* Vc = &Vl[cur][0];

        // S^T = K Q^T  (q carries 0.125*log2e scale)
        f32x4 s[4] = {};
#pragma unroll
        for (int ks = 0; ks < 2; ks++)
#pragma unroll
            for (int tt = 0; tt < 4; tt++) {
                int row = tt * 16 + r;
                half8 kf = *(const half8*)(Kc + row * 64 + (((4 * ks + g) ^ (row & 7)) << 3));
                s[tt] = __builtin_amdgcn_mfma_f32_16x16x32_f16(kf, qf[ks], s[tt], 0, 0, 0);
            }

        // online softmax, log2 domain, one q per lane
        float mx = -1e30f;
#pragma unroll
        for (int tt = 0; tt < 4; tt++)
            mx = fmaxf(mx, fmaxf(fmaxf(s[tt][0], s[tt][1]), fmaxf(s[tt][2], s[tt][3])));
        mx = fmaxf(mx, __shfl_xor(mx, 16, 64));
        mx = fmaxf(mx, __shfl_xor(mx, 32, 64));
        if (!__all(mx <= m + 11.0f)) {   // defer-max: skip rescale when growth is small
            float mn = fmaxf(m, mx);
            float fac = exp2_fast(m - mn);
            lsum *= fac;
#pragma unroll
            for (int cf = 0; cf < 4; cf++) {
                o[cf][0] *= fac; o[cf][1] *= fac; o[cf][2] *= fac; o[cf][3] *= fac;
            }
            m = mn;
        }
        float rs = 0.f;
#pragma unroll
        for (int tt = 0; tt < 4; tt++)
#pragma unroll
            for (int e = 0; e < 4; e++) {
                float p = exp2_fast(s[tt][e] - m);
                s[tt][e] = p;
                rs += p;
            }
        rs += __shfl_xor(rs, 16, 64);
        rs += __shfl_xor(rs, 32, 64);
        lsum += rs;

        // pack P to fp16 pairs and store to per-wave swizzled LDS:
        // pair-col pc = kv>>1 = 8tt + 2g + u ; chunk = pc>>2 = 2tt + (g>>1); swz chunk ^= (q&7)
        half_t* Pw = &Pl[w][0];
#pragma unroll
        for (int tt = 0; tt < 4; tt++) {
            fp16x2 a = __builtin_amdgcn_cvt_pkrtz(s[tt][0], s[tt][1]);
            fp16x2 b = __builtin_amdgcn_cvt_pkrtz(s[tt][2], s[tt][3]);
            half4v v4;
            v4[0] = (half_t)a[0]; v4[1] = (half_t)a[1];
            v4[2] = (half_t)b[0]; v4[3] = (half_t)b[1];
            *(half4v*)(Pw + r * 64 + (((2 * tt + (g >> 1)) ^ (r & 7)) << 3) + ((2 * g) & 3) * 2) = v4;
        }

        // O^T += V^T P^T : pf = P^T[kv = 32ks2 + 8g + e][q = r]
#pragma unroll
        for (int ks2 = 0; ks2 < 2; ks2++) {
            half8 pf = *(const half8*)(Pw + r * 64 + (((4 * ks2 + g) ^ (r & 7)) << 3));
#pragma unroll
            for (int cf = 0; cf < 4; cf++) {
                int row = cf * 16 + r;
                half8 vf = *(const half8*)(Vc + row * 64 + (((4 * ks2 + g) ^ (row & 7)) << 3));
                o[cf] = __builtin_amdgcn_mfma_f32_16x16x32_f16(vf, pf, o[cf], 0, 0, 0);
            }
        }
        __syncthreads();
        cur ^= 1;
    }

    int b = bh >> 4, h = bh & 15;
    int n = q0 + w * 16 + r;
    float inv = 1.0f / lsum;
#pragma unroll
    for (int cf = 0; cf < 4; cf++) {
        half4v ov;
#pragma unroll
        for (int reg = 0; reg < 4; reg++) ov[reg] = (half_t)(o[cf][reg] * inv);
        *(half4v*)(aoh + ((size_t)b * 2048 + n) * 1024 + h * 64 + cf * 16 + g * 4) = ov;
    }
}

// ---------------- proj GEMM: fp16, BK=64, + bias, f32 out ----------------
__global__ __launch_bounds__(256) void gemm_proj(
    const half_t* __restrict__ A, const half_t* __restrict__ Bt,
    const float* __restrict__ bias, float* __restrict__ out) {
    const int K = 1024;
    __shared__ __align__(16) half_t Al[128 * 64];
    __shared__ __align__(16) half_t Bl[128 * 64];
    int tid = threadIdx.x, w = tid >> 6, l = tid & 63;
    int wr = w >> 1, wc = w & 1, g = l >> 4, r = l & 15;
    int m0 = blockIdx.x * 128, n0 = blockIdx.y * 128;
    f32x4 acc[4][4] = {};

    for (int k0 = 0; k0 < K; k0 += 64) {
#pragma unroll
        for (int p = 0; p < 4; p++) {
            int ci = (p * 4 + w) * 64 + l;
            int row = ci >> 3, c = ci & 7;
            int lc = c ^ (row & 7);
            gl_lds16(A + (size_t)(m0 + row) * K + k0 + lc * 8, Al + (p * 4 + w) * 512);
            gl_lds16(Bt + (size_t)(n0 + row) * K + k0 + lc * 8, Bl + (p * 4 + w) * 512);
        }
        __syncthreads();
#pragma unroll
        for (int ks = 0; ks < 2; ks++) {
            half8 af[4], bf[4];
#pragma unroll
            for (int i = 0; i < 4; i++) {
                int row = wr * 64 + i * 16 + r;
                af[i] = *(const half8*)(Al + row * 64 + (((4 * ks + g) ^ (row & 7)) << 3));
                int rowb = wc * 64 + i * 16 + r;
                bf[i] = *(const half8*)(Bl + rowb * 64 + (((4 * ks + g) ^ (rowb & 7)) << 3));
            }
#pragma unroll
            for (int i = 0; i < 4; i++)
#pragma unroll
                for (int j = 0; j < 4; j++)
                    acc[i][j] = __builtin_amdgcn_mfma_f32_16x16x32_f16(af[i], bf[j], acc[i][j], 0, 0, 0);
        }
        __syncthreads();
    }

#pragma unroll
    for (int i = 0; i < 4; i++)
#pragma unroll
        for (int j = 0; j < 4; j++) {
            int gcol = n0 + wc * 64 + j * 16 + r;
            float bv = bias[gcol];
#pragma unroll
            for (int rr = 0; rr < 4; rr++) {
                int grow = m0 + wr * 64 + i * 16 + g * 4 + rr;
                out[(size_t)grow * 1024 + gcol] = acc[i][j][rr] + bv;
            }
        }
}

// ---------------- launch ----------------
extern "C" void kernel_launch(void* const* d_in, const int* in_sizes, int n_in,
                              void* d_out, int out_size, void* d_ws, size_t ws_size,
                              hipStream_t stream) {
    const float* x = (const float*)d_in[0];
    const float* Wqkv = (const float*)d_in[1];
    const float* Wproj = (const float*)d_in[2];
    const float* bproj = (const float*)d_in[3];
    const float* qscale = (const float*)d_in[4];
    const float* kscale = (const float*)d_in[5];
    float* out = (float*)d_out;

    char* ws = (char*)d_ws;
    unsigned short* xhi = (unsigned short*)(ws + 0);          //  8.0 MB
    unsigned short* xlo = (unsigned short*)(ws + 8388608);    //  8.0 MB
    unsigned short* whit = (unsigned short*)(ws + 16777216);  //  6.0 MB
    unsigned short* wlot = (unsigned short*)(ws + 23068672);  //  6.0 MB
    half_t* wpt = (half_t*)(ws + 29360128);                   //  2.0 MB
    half_t* qh = (half_t*)(ws + 31457280);                    //  8.0 MB (b,h,n,f)
    half_t* kh = (half_t*)(ws + 39845888);                    //  8.0 MB (b,h,n,f)
    half_t* vth = (half_t*)(ws + 48234496);                   //  8.0 MB (b,h,f,n)
    half_t* aoh = (half_t*)(ws + 56623104);                   //  8.0 MB (b,n,c)

    prep_x<<<4096, 256, 0, stream>>>(x, xhi, xlo, 4194304);
    prep_wqkv<<<dim3(96, 32), dim3(32, 8), 0, stream>>>(Wqkv, whit, wlot);
    prep_wproj<<<dim3(32, 32), dim3(32, 8), 0, stream>>>(Wproj, wpt);
    gemm_qkv<<<dim3(32, 24), 256, 0, stream>>>(xhi, xlo, whit, wlot, qh, kh, vth);
    rmsnorm_qk<<<8192, 256, 0, stream>>>(qh, kh, qscale, kscale);
    attn<<<dim3(16, 32), 512, 0, stream>>>(qh, kh, vth, aoh);
    gemm_proj<<<dim3(32, 8), 256, 0, stream>>>(aoh, wpt, bproj, out);
}

// Round 4
// 152.871 us; speedup vs baseline: 1.6114x; 1.2746x over previous
//
#include <hip/hip_runtime.h>

// Problem constants: B=2, N=2048, C=1024, H=16, hd=64
// x:(2,2048,1024) f32; Wqkv:(1024,3072); Wproj:(1024,1024); bproj:(1024); q_scale,k_scale:(64)
// out:(2,2048,1024) f32

typedef _Float16 half_t;
typedef __attribute__((ext_vector_type(2))) __fp16 fp16x2;
typedef __attribute__((ext_vector_type(4))) _Float16 half4v;
typedef __attribute__((ext_vector_type(8))) _Float16 half8;
typedef __attribute__((ext_vector_type(4))) float f32x4;

#define DI __device__ __forceinline__

DI void gl_lds16(const void* g, void* l) {
    __builtin_amdgcn_global_load_lds((const __attribute__((address_space(1))) void*)g,
                                     (__attribute__((address_space(3))) void*)l, 16, 0, 0);
}

DI float exp2_fast(float x) {
    float r;
    asm("v_exp_f32 %0, %1" : "=v"(r) : "v"(x));
    return r;
}

// ---------------- prep kernels ----------------

// x f32 -> fp16
__global__ void prep_x(const float* __restrict__ x, half_t* __restrict__ xh, int n) {
    int i = (blockIdx.x * 256 + threadIdx.x) * 4;
    if (i >= n) return;
    float4 v = *(const float4*)(x + i);
    half4v o;
    o[0] = (half_t)v.x; o[1] = (half_t)v.y; o[2] = (half_t)v.z; o[3] = (half_t)v.w;
    *(half4v*)(xh + i) = o;
}

// Wqkv (1024 x 3072) f32 -> transposed fp16 (3072 x 1024)
__global__ void prep_wqkv(const float* __restrict__ w, half_t* __restrict__ wt) {
    __shared__ float t[32][33];
    int c0 = blockIdx.x * 32, r0 = blockIdx.y * 32;
    int tx = threadIdx.x, ty = threadIdx.y; // 32x8
#pragma unroll
    for (int i = 0; i < 4; i++)
        t[ty + 8 * i][tx] = w[(size_t)(r0 + ty + 8 * i) * 3072 + c0 + tx];
    __syncthreads();
#pragma unroll
    for (int i = 0; i < 4; i++)
        wt[(size_t)(c0 + ty + 8 * i) * 1024 + r0 + tx] = (half_t)t[tx][ty + 8 * i];
}

// Wproj (1024 x 1024) f32 -> transposed fp16 (1024 x 1024)
__global__ void prep_wproj(const float* __restrict__ w, half_t* __restrict__ wt) {
    __shared__ float t[32][33];
    int c0 = blockIdx.x * 32, r0 = blockIdx.y * 32;
    int tx = threadIdx.x, ty = threadIdx.y;
#pragma unroll
    for (int i = 0; i < 4; i++)
        t[ty + 8 * i][tx] = w[(size_t)(r0 + ty + 8 * i) * 1024 + c0 + tx];
    __syncthreads();
#pragma unroll
    for (int i = 0; i < 4; i++)
        wt[(size_t)(c0 + ty + 8 * i) * 1024 + r0 + tx] = (half_t)t[tx][ty + 8 * i];
}

// ---------------- QKV GEMM: fp16 single-pass, BK=64, double-buffered LDS ----------------
// C[4096][3072] = x[4096][1024] @ Wqkv ; A row-major M x K fp16, B transposed N x K fp16.
// Epilogue scatters to q/k (b,h,n,f) fp16 and v transposed (b,h,f,n) fp16.
__global__ __launch_bounds__(256) void gemm_qkv(
    const half_t* __restrict__ A, const half_t* __restrict__ Bt,
    half_t* __restrict__ qh, half_t* __restrict__ kh, half_t* __restrict__ vth) {
    const int K = 1024;
    __shared__ __align__(16) half_t Al[2][128 * 64];
    __shared__ __align__(16) half_t Bl[2][128 * 64];
    int tid = threadIdx.x;
    int w = tid >> 6, l = tid & 63;
    int wr = w >> 1, wc = w & 1;
    int g = l >> 4, r = l & 15;
    int m0 = blockIdx.x * 128, n0 = blockIdx.y * 128;
    f32x4 acc[4][4] = {};

    // stage K-tile kt (64 cols) into buffer buf: 1024 chunks of 16B per matrix
#define STAGE_QKV(kt, buf)                                                        \
    {                                                                             \
        _Pragma("unroll")                                                         \
        for (int p = 0; p < 4; p++) {                                             \
            int ci = p * 256 + tid;                                               \
            int row = ci >> 3, c = ci & 7, lc = c ^ (row & 7);                    \
            gl_lds16(A + (size_t)(m0 + row) * K + (kt) * 64 + lc * 8,             \
                     &Al[buf][0] + ci * 8);                                       \
            gl_lds16(Bt + (size_t)(n0 + row) * K + (kt) * 64 + lc * 8,            \
                     &Bl[buf][0] + ci * 8);                                       \
        }                                                                         \
    }

    STAGE_QKV(0, 0);
    __syncthreads();
    int cur = 0;
    for (int kt = 0; kt < 16; kt++) {
        if (kt < 15) STAGE_QKV(kt + 1, cur ^ 1);
#pragma unroll
        for (int ks = 0; ks < 2; ks++) {
            half8 af[4], bf[4];
#pragma unroll
            for (int i = 0; i < 4; i++) {
                int row = wr * 64 + i * 16 + r;
                af[i] = *(const half8*)(&Al[cur][0] + row * 64 + (((4 * ks + g) ^ (row & 7)) << 3));
                int rowb = wc * 64 + i * 16 + r;
                bf[i] = *(const half8*)(&Bl[cur][0] + rowb * 64 + (((4 * ks + g) ^ (rowb & 7)) << 3));
            }
#pragma unroll
            for (int i = 0; i < 4; i++)
#pragma unroll
                for (int j = 0; j < 4; j++)
                    acc[i][j] = __builtin_amdgcn_mfma_f32_16x16x32_f16(af[i], bf[j], acc[i][j], 0, 0, 0);
        }
        __syncthreads();
        cur ^= 1;
    }

    // epilogue: D mapping col=l&15, row=(l>>4)*4+reg
#pragma unroll
    for (int i = 0; i < 4; i++)
#pragma unroll
        for (int j = 0; j < 4; j++) {
            int gcol = n0 + wc * 64 + j * 16 + r;
            int t = gcol >> 10;
            int h = (gcol >> 6) & 15;
            int f = gcol & 63;
            int growb = m0 + wr * 64 + i * 16 + g * 4;
            int b = growb >> 11;
            int n = growb & 2047;
            int bh = b * 16 + h;
            if (t == 2) {
                half4v pv;
#pragma unroll
                for (int rr = 0; rr < 4; rr++) pv[rr] = (half_t)acc[i][j][rr];
                *(half4v*)(vth + ((size_t)bh * 64 + f) * 2048 + n) = pv;
            } else {
                half_t* dst = (t == 0 ? qh : kh);
#pragma unroll
                for (int rr = 0; rr < 4; rr++)
                    dst[((size_t)bh * 2048 + n + rr) * 64 + f] = (half_t)acc[i][j][rr];
            }
        }
}

// ---------------- RMSNorm on q,k (in place, fp16) ----------------
// folds (hd^-0.5 * log2e) into q so attention logits are in log2 units
__global__ void rmsnorm_qk(half_t* __restrict__ qh, half_t* __restrict__ kh,
                           const float* __restrict__ qs, const float* __restrict__ ks2) {
    int tid = blockIdx.x * 256 + threadIdx.x;
    int row = tid >> 4;  // 0..131071 : first 65536 rows = q, rest = k
    int lq = tid & 15;
    bool isq = row < 65536;
    half_t* base = isq ? (qh + (size_t)row * 64) : (kh + (size_t)(row - 65536) * 64);
    const float* sc = isq ? qs : ks2;
    float extra = isq ? (0.125f * 1.44269504f) : 1.0f;
    half4v v = *(half4v*)(base + lq * 4);
    float f0 = (float)v[0], f1 = (float)v[1], f2 = (float)v[2], f3 = (float)v[3];
    float ss = f0 * f0 + f1 * f1 + f2 * f2 + f3 * f3;
#pragma unroll
    for (int d = 1; d < 16; d <<= 1) ss += __shfl_xor(ss, d, 64);
    float rms = sqrtf(ss) * 0.125f;  // ||x|| / sqrt(64)
    float inv = extra / (rms + 1e-8f);
    half4v o;
    o[0] = (half_t)(f0 * sc[lq * 4 + 0] * inv);
    o[1] = (half_t)(f1 * sc[lq * 4 + 1] * inv);
    o[2] = (half_t)(f2 * sc[lq * 4 + 2] * inv);
    o[3] = (half_t)(f3 * sc[lq * 4 + 3] * inv);
    *(half4v*)(base + lq * 4) = o;
}

// ---------------- flash attention, swapped-QK in-register softmax ----------------
// grid (16 q-tiles, 32 bh). Block: 512 thr = 8 waves, each wave 16 q-rows (1 q/lane).
// S^T = mfma(K_frag, Q_frag): lane holds S^T[kv=16t+4g+reg][q=r].
// PV as O^T = mfma(V^T_frag, P^T_frag); P repacked via per-wave swizzled LDS.
__global__ __launch_bounds__(512) void attn(
    const half_t* __restrict__ qh, const half_t* __restrict__ kh,
    const half_t* __restrict__ vth, half_t* __restrict__ aoh) {
    int bh = blockIdx.y;
    int q0 = blockIdx.x * 128;
    const half_t* Qp = qh + (size_t)bh * 2048 * 64;
    const half_t* Kp = kh + (size_t)bh * 2048 * 64;
    const half_t* Vp = vth + (size_t)bh * 64 * 2048;  // (feat, n)
    __shared__ __align__(16) half_t Kl[2][64 * 64];
    __shared__ __align__(16) half_t Vl[2][64 * 64];   // [feat][kv]
    __shared__ __align__(16) half_t Pl[8][16 * 64];   // per-wave: 16 q x 64 kv (chunk-swizzled)
    int tid = threadIdx.x, w = tid >> 6, l = tid & 63, g = l >> 4, r = l & 15;

    // staging coords: 512 chunks of 16B per 64x64 fp16 buffer, 1 K-chunk + 1 V-chunk per thread
    int srow = tid >> 3, sc = tid & 7, slc = sc ^ (srow & 7);

    // Q fragment: Q[q=r][hd = 32ks + 8g + e]  (serves as B-operand of swapped QK^T)
    half8 qf[2];
#pragma unroll
    for (int ks = 0; ks < 2; ks++)
        qf[ks] = *(const half8*)(Qp + (size_t)(q0 + w * 16 + r) * 64 + ks * 32 + g * 8);

    f32x4 o[4] = {};          // O^T[d = 16cf + 4g + reg][q = r]
    float m = -1e30f, lsum = 0.f;

    // prologue: stage tile 0
    gl_lds16(Kp + (size_t)srow * 64 + slc * 8, &Kl[0][0] + tid * 8);
    gl_lds16(Vp + (size_t)srow * 2048 + slc * 8, &Vl[0][0] + tid * 8);
    __syncthreads();

    int cur = 0;
    for (int t = 0; t < 32; t++) {
        if (t < 31) {
            int kv1 = (t + 1) * 64;
            gl_lds16(Kp + (size_t)(kv1 + srow) * 64 + slc * 8, &Kl[cur ^ 1][0] + tid * 8);
            gl_lds16(Vp + (size_t)srow * 2048 + kv1 + slc * 8, &Vl[cur ^ 1][0] + tid * 8);
        }
        const half_t* Kc = &Kl[cur][0];
        const half_t* Vc = &Vl[cur][0];

        // S^T = K Q^T  (q carries 0.125*log2e scale)
        f32x4 s[4] = {};
#pragma unroll
        for (int ks = 0; ks < 2; ks++)
#pragma unroll
            for (int tt = 0; tt < 4; tt++) {
                int row = tt * 16 + r;
                half8 kf = *(const half8*)(Kc + row * 64 + (((4 * ks + g) ^ (row & 7)) << 3));
                s[tt] = __builtin_amdgcn_mfma_f32_16x16x32_f16(kf, qf[ks], s[tt], 0, 0, 0);
            }

        // online softmax, log2 domain, one q per lane
        float mx = -1e30f;
#pragma unroll
        for (int tt = 0; tt < 4; tt++)
            mx = fmaxf(mx, fmaxf(fmaxf(s[tt][0], s[tt][1]), fmaxf(s[tt][2], s[tt][3])));
        mx = fmaxf(mx, __shfl_xor(mx, 16, 64));
        mx = fmaxf(mx, __shfl_xor(mx, 32, 64));
        if (!__all(mx <= m + 11.0f)) {   // defer-max: skip rescale when growth is small
            float mn = fmaxf(m, mx);
            float fac = exp2_fast(m - mn);
            lsum *= fac;
#pragma unroll
            for (int cf = 0; cf < 4; cf++) {
                o[cf][0] *= fac; o[cf][1] *= fac; o[cf][2] *= fac; o[cf][3] *= fac;
            }
            m = mn;
        }
        float rs = 0.f;
#pragma unroll
        for (int tt = 0; tt < 4; tt++)
#pragma unroll
            for (int e = 0; e < 4; e++) {
                float p = exp2_fast(s[tt][e] - m);
                s[tt][e] = p;
                rs += p;
            }
        rs += __shfl_xor(rs, 16, 64);
        rs += __shfl_xor(rs, 32, 64);
        lsum += rs;

        // pack P to fp16 pairs and store to per-wave swizzled LDS:
        // pair-col pc = kv>>1 = 8tt + 2g + u ; chunk = pc>>2 = 2tt + (g>>1); swz chunk ^= (q&7)
        half_t* Pw = &Pl[w][0];
#pragma unroll
        for (int tt = 0; tt < 4; tt++) {
            fp16x2 a = __builtin_amdgcn_cvt_pkrtz(s[tt][0], s[tt][1]);
            fp16x2 b = __builtin_amdgcn_cvt_pkrtz(s[tt][2], s[tt][3]);
            half4v v4;
            v4[0] = (half_t)a[0]; v4[1] = (half_t)a[1];
            v4[2] = (half_t)b[0]; v4[3] = (half_t)b[1];
            *(half4v*)(Pw + r * 64 + (((2 * tt + (g >> 1)) ^ (r & 7)) << 3) + ((2 * g) & 3) * 2) = v4;
        }

        // O^T += V^T P^T : pf = P^T[kv = 32ks2 + 8g + e][q = r]
#pragma unroll
        for (int ks2 = 0; ks2 < 2; ks2++) {
            half8 pf = *(const half8*)(Pw + r * 64 + (((4 * ks2 + g) ^ (r & 7)) << 3));
#pragma unroll
            for (int cf = 0; cf < 4; cf++) {
                int row = cf * 16 + r;
                half8 vf = *(const half8*)(Vc + row * 64 + (((4 * ks2 + g) ^ (row & 7)) << 3));
                o[cf] = __builtin_amdgcn_mfma_f32_16x16x32_f16(vf, pf, o[cf], 0, 0, 0);
            }
        }
        __syncthreads();
        cur ^= 1;
    }

    int b = bh >> 4, h = bh & 15;
    int n = q0 + w * 16 + r;
    float inv = 1.0f / lsum;
#pragma unroll
    for (int cf = 0; cf < 4; cf++) {
        half4v ov;
#pragma unroll
        for (int reg = 0; reg < 4; reg++) ov[reg] = (half_t)(o[cf][reg] * inv);
        *(half4v*)(aoh + ((size_t)b * 2048 + n) * 1024 + h * 64 + cf * 16 + g * 4) = ov;
    }
}

// ---------------- proj GEMM: fp16, BK=64, + bias, f32 out ----------------
__global__ __launch_bounds__(256) void gemm_proj(
    const half_t* __restrict__ A, const half_t* __restrict__ Bt,
    const float* __restrict__ bias, float* __restrict__ out) {
    const int K = 1024;
    __shared__ __align__(16) half_t Al[128 * 64];
    __shared__ __align__(16) half_t Bl[128 * 64];
    int tid = threadIdx.x, w = tid >> 6, l = tid & 63;
    int wr = w >> 1, wc = w & 1, g = l >> 4, r = l & 15;
    int m0 = blockIdx.x * 128, n0 = blockIdx.y * 128;
    f32x4 acc[4][4] = {};

    for (int k0 = 0; k0 < K; k0 += 64) {
#pragma unroll
        for (int p = 0; p < 4; p++) {
            int ci = (p * 4 + w) * 64 + l;
            int row = ci >> 3, c = ci & 7;
            int lc = c ^ (row & 7);
            gl_lds16(A + (size_t)(m0 + row) * K + k0 + lc * 8, Al + (p * 4 + w) * 512);
            gl_lds16(Bt + (size_t)(n0 + row) * K + k0 + lc * 8, Bl + (p * 4 + w) * 512);
        }
        __syncthreads();
#pragma unroll
        for (int ks = 0; ks < 2; ks++) {
            half8 af[4], bf[4];
#pragma unroll
            for (int i = 0; i < 4; i++) {
                int row = wr * 64 + i * 16 + r;
                af[i] = *(const half8*)(Al + row * 64 + (((4 * ks + g) ^ (row & 7)) << 3));
                int rowb = wc * 64 + i * 16 + r;
                bf[i] = *(const half8*)(Bl + rowb * 64 + (((4 * ks + g) ^ (rowb & 7)) << 3));
            }
#pragma unroll
            for (int i = 0; i < 4; i++)
#pragma unroll
                for (int j = 0; j < 4; j++)
                    acc[i][j] = __builtin_amdgcn_mfma_f32_16x16x32_f16(af[i], bf[j], acc[i][j], 0, 0, 0);
        }
        __syncthreads();
    }

#pragma unroll
    for (int i = 0; i < 4; i++)
#pragma unroll
        for (int j = 0; j < 4; j++) {
            int gcol = n0 + wc * 64 + j * 16 + r;
            float bv = bias[gcol];
#pragma unroll
            for (int rr = 0; rr < 4; rr++) {
                int grow = m0 + wr * 64 + i * 16 + g * 4 + rr;
                out[(size_t)grow * 1024 + gcol] = acc[i][j][rr] + bv;
            }
        }
}

// ---------------- launch ----------------
extern "C" void kernel_launch(void* const* d_in, const int* in_sizes, int n_in,
                              void* d_out, int out_size, void* d_ws, size_t ws_size,
                              hipStream_t stream) {
    const float* x = (const float*)d_in[0];
    const float* Wqkv = (const float*)d_in[1];
    const float* Wproj = (const float*)d_in[2];
    const float* bproj = (const float*)d_in[3];
    const float* qscale = (const float*)d_in[4];
    const float* kscale = (const float*)d_in[5];
    float* out = (float*)d_out;

    char* ws = (char*)d_ws;
    half_t* xh  = (half_t*)(ws + 0);         //  8.0 MB (4096 x 1024 fp16)
    half_t* wqt = (half_t*)(ws + 8388608);   //  6.0 MB (3072 x 1024 fp16, transposed)
    half_t* wpt = (half_t*)(ws + 14680064);  //  2.0 MB (1024 x 1024 fp16, transposed)
    half_t* qh  = (half_t*)(ws + 16777216);  //  8.0 MB (b,h,n,f)
    half_t* kh  = (half_t*)(ws + 25165824);  //  8.0 MB (b,h,n,f)
    half_t* vth = (half_t*)(ws + 33554432);  //  8.0 MB (b,h,f,n)
    half_t* aoh = (half_t*)(ws + 41943040);  //  8.0 MB (b,n,c)

    prep_x<<<4096, 256, 0, stream>>>(x, xh, 4194304);
    prep_wqkv<<<dim3(96, 32), dim3(32, 8), 0, stream>>>(Wqkv, wqt);
    prep_wproj<<<dim3(32, 32), dim3(32, 8), 0, stream>>>(Wproj, wpt);
    gemm_qkv<<<dim3(32, 24), 256, 0, stream>>>(xh, wqt, qh, kh, vth);
    rmsnorm_qk<<<8192, 256, 0, stream>>>(qh, kh, qscale, kscale);
    attn<<<dim3(16, 32), 512, 0, stream>>>(qh, kh, vth, aoh);
    gemm_proj<<<dim3(32, 8), 256, 0, stream>>>(aoh, wpt, bproj, out);
}

// Round 5
// 138.352 us; speedup vs baseline: 1.7805x; 1.1049x over previous
//
#include <hip/hip_runtime.h>

// Problem constants: B=2, N=2048, C=1024, H=16, hd=64
// x:(2,2048,1024) f32; Wqkv:(1024,3072); Wproj:(1024,1024); bproj:(1024); q_scale,k_scale:(64)
// out:(2,2048,1024) f32

typedef _Float16 half_t;
typedef __attribute__((ext_vector_type(2))) __fp16 fp16x2;
typedef __attribute__((ext_vector_type(4))) _Float16 half4v;
typedef __attribute__((ext_vector_type(8))) _Float16 half8;
typedef __attribute__((ext_vector_type(4))) float f32x4;

#define DI __device__ __forceinline__

DI void gl_lds16(const void* g, void* l) {
    __builtin_amdgcn_global_load_lds((const __attribute__((address_space(1))) void*)g,
                                     (__attribute__((address_space(3))) void*)l, 16, 0, 0);
}

DI float exp2_fast(float x) {
    float r;
    asm("v_exp_f32 %0, %1" : "=v"(r) : "v"(x));
    return r;
}

// ---------------- prep kernels ----------------

// x f32 -> fp16
__global__ void prep_x(const float* __restrict__ x, half_t* __restrict__ xh, int n) {
    int i = (blockIdx.x * 256 + threadIdx.x) * 4;
    if (i >= n) return;
    float4 v = *(const float4*)(x + i);
    half4v o;
    o[0] = (half_t)v.x; o[1] = (half_t)v.y; o[2] = (half_t)v.z; o[3] = (half_t)v.w;
    *(half4v*)(xh + i) = o;
}

// Wqkv (1024 x 3072) f32 -> transposed fp16 (3072 x 1024)
__global__ void prep_wqkv(const float* __restrict__ w, half_t* __restrict__ wt) {
    __shared__ float t[32][33];
    int c0 = blockIdx.x * 32, r0 = blockIdx.y * 32;
    int tx = threadIdx.x, ty = threadIdx.y; // 32x8
#pragma unroll
    for (int i = 0; i < 4; i++)
        t[ty + 8 * i][tx] = w[(size_t)(r0 + ty + 8 * i) * 3072 + c0 + tx];
    __syncthreads();
#pragma unroll
    for (int i = 0; i < 4; i++)
        wt[(size_t)(c0 + ty + 8 * i) * 1024 + r0 + tx] = (half_t)t[tx][ty + 8 * i];
}

// Wproj (1024 x 1024) f32 -> transposed fp16 (1024 x 1024)
__global__ void prep_wproj(const float* __restrict__ w, half_t* __restrict__ wt) {
    __shared__ float t[32][33];
    int c0 = blockIdx.x * 32, r0 = blockIdx.y * 32;
    int tx = threadIdx.x, ty = threadIdx.y;
#pragma unroll
    for (int i = 0; i < 4; i++)
        t[ty + 8 * i][tx] = w[(size_t)(r0 + ty + 8 * i) * 1024 + c0 + tx];
    __syncthreads();
#pragma unroll
    for (int i = 0; i < 4; i++)
        wt[(size_t)(c0 + ty + 8 * i) * 1024 + r0 + tx] = (half_t)t[tx][ty + 8 * i];
}

// ---------------- QKV GEMM: fp16, BK=64, dbuf LDS, fused RMSNorm epilogue ----------------
// C[4096][3072] = x[4096][1024] @ Wqkv. Each block's 128-col span lies in exactly one of
// {q,k,v} (1024 % 128 == 0). q/k epilogue: RMSNorm over hd=64 from f32 acc (4-step shfl
// reduce over the 16-lane r-group), fold q_scale/k_scale and (hd^-0.5 * log2e) into q.
// v epilogue: store transposed (b,h,f,n).
__global__ __launch_bounds__(256) void gemm_qkv(
    const half_t* __restrict__ A, const half_t* __restrict__ Bt,
    const float* __restrict__ qs, const float* __restrict__ ks,
    half_t* __restrict__ qh, half_t* __restrict__ kh, half_t* __restrict__ vth) {
    const int K = 1024;
    __shared__ __align__(16) half_t Al[2][128 * 64];
    __shared__ __align__(16) half_t Bl[2][128 * 64];
    int tid = threadIdx.x;
    int w = tid >> 6, l = tid & 63;
    int wr = w >> 1, wc = w & 1;
    int g = l >> 4, r = l & 15;
    int m0 = blockIdx.x * 128, n0 = blockIdx.y * 128;
    f32x4 acc[4][4] = {};

#define STAGE_QKV(kt, buf)                                                        \
    {                                                                             \
        _Pragma("unroll")                                                         \
        for (int p = 0; p < 4; p++) {                                             \
            int ci = p * 256 + tid;                                               \
            int row = ci >> 3, c = ci & 7, lc = c ^ (row & 7);                    \
            gl_lds16(A + (size_t)(m0 + row) * K + (kt) * 64 + lc * 8,             \
                     &Al[buf][0] + ci * 8);                                       \
            gl_lds16(Bt + (size_t)(n0 + row) * K + (kt) * 64 + lc * 8,            \
                     &Bl[buf][0] + ci * 8);                                       \
        }                                                                         \
    }

    STAGE_QKV(0, 0);
    __syncthreads();
    int cur = 0;
    for (int kt = 0; kt < 16; kt++) {
        if (kt < 15) STAGE_QKV(kt + 1, cur ^ 1);
#pragma unroll
        for (int ks2 = 0; ks2 < 2; ks2++) {
            half8 af[4], bf[4];
#pragma unroll
            for (int i = 0; i < 4; i++) {
                int row = wr * 64 + i * 16 + r;
                af[i] = *(const half8*)(&Al[cur][0] + row * 64 + (((4 * ks2 + g) ^ (row & 7)) << 3));
                int rowb = wc * 64 + i * 16 + r;
                bf[i] = *(const half8*)(&Bl[cur][0] + rowb * 64 + (((4 * ks2 + g) ^ (rowb & 7)) << 3));
            }
#pragma unroll
            for (int i = 0; i < 4; i++)
#pragma unroll
                for (int j = 0; j < 4; j++)
                    acc[i][j] = __builtin_amdgcn_mfma_f32_16x16x32_f16(af[i], bf[j], acc[i][j], 0, 0, 0);
        }
        __syncthreads();
        cur ^= 1;
    }

    int tsec = n0 >> 10;  // 0=q, 1=k, 2=v (uniform per block)
    if (tsec == 2) {
#pragma unroll
        for (int i = 0; i < 4; i++)
#pragma unroll
            for (int j = 0; j < 4; j++) {
                int gcol = n0 + wc * 64 + j * 16 + r;
                int h = (gcol >> 6) & 15;
                int f = gcol & 63;
                int growb = m0 + wr * 64 + i * 16 + g * 4;
                int b = growb >> 11;
                int n = growb & 2047;
                half4v pv;
#pragma unroll
                for (int rr = 0; rr < 4; rr++) pv[rr] = (half_t)acc[i][j][rr];
                *(half4v*)(vth + ((size_t)(b * 16 + h) * 64 + f) * 2048 + n) = pv;
            }
    } else {
        const float* sc = (tsec == 0) ? qs : ks;
        half_t* dst = (tsec == 0) ? qh : kh;
        float extra = (tsec == 0) ? (0.125f * 1.44269504f) : 1.0f;  // fold hd^-0.5*log2e into q
        float scv[4];
#pragma unroll
        for (int j = 0; j < 4; j++) scv[j] = sc[j * 16 + r];
#pragma unroll
        for (int i = 0; i < 4; i++)
#pragma unroll
            for (int rr = 0; rr < 4; rr++) {
                float ss = 0.f;
#pragma unroll
                for (int j = 0; j < 4; j++) ss += acc[i][j][rr] * acc[i][j][rr];
#pragma unroll
                for (int d = 1; d < 16; d <<= 1) ss += __shfl_xor(ss, d, 64);
                float inv = extra / (sqrtf(ss) * 0.125f + 1e-8f);  // rms = ||row||/8
                int grow = m0 + wr * 64 + i * 16 + g * 4 + rr;
                int b = grow >> 11;
                int n = grow & 2047;
#pragma unroll
                for (int j = 0; j < 4; j++) {
                    int gcol = n0 + wc * 64 + j * 16 + r;
                    int h = (gcol >> 6) & 15;
                    int f = gcol & 63;
                    dst[((size_t)(b * 16 + h) * 2048 + n) * 64 + f] =
                        (half_t)(acc[i][j][rr] * inv * scv[j]);
                }
            }
    }
}

// ---------------- flash attention, swapped-QK in-register softmax ----------------
// grid (16 q-tiles, 32 bh). Block: 512 thr = 8 waves, each wave 16 q-rows (1 q/lane).
// S^T = mfma(K_frag, Q_frag): lane holds S^T[kv=16tt+4g+reg][q=r].
// PV as O^T = mfma(V^T_frag, P^T_frag); P repacked via per-wave swizzled LDS.
// All LDS offsets hoisted pre-loop; t-loop unrolled x2 for compile-time dbuf index.
__global__ __launch_bounds__(512, 4) void attn(
    const half_t* __restrict__ qh, const half_t* __restrict__ kh,
    const half_t* __restrict__ vth, half_t* __restrict__ aoh) {
    int bh = blockIdx.y;
    int q0 = blockIdx.x * 128;
    const half_t* Qp = qh + (size_t)bh * 2048 * 64;
    const half_t* Kp = kh + (size_t)bh * 2048 * 64;
    const half_t* Vp = vth + (size_t)bh * 64 * 2048;  // (feat, n)
    __shared__ __align__(16) half_t Kl[2][64 * 64];
    __shared__ __align__(16) half_t Vl[2][64 * 64];   // [feat][kv]
    __shared__ __align__(16) half_t Pl[8][16 * 64];   // per-wave: 16 q x 64 kv (chunk-swizzled)
    int tid = threadIdx.x, w = tid >> 6, l = tid & 63, g = l >> 4, r = l & 15;

    // staging coords: 512 chunks of 16B per 64x64 fp16 buffer
    int srow = tid >> 3, sc = tid & 7, slc = sc ^ (srow & 7);
    const half_t* kst = Kp + (size_t)srow * 64 + slc * 8;
    const half_t* vst = Vp + (size_t)srow * 2048 + slc * 8;

    // hoisted LDS element-offsets (loop-invariant)
    int koff[8], voff[8], poffw[4], poffr[2];
#pragma unroll
    for (int ks = 0; ks < 2; ks++)
#pragma unroll
        for (int tt = 0; tt < 4; tt++) {
            int row = tt * 16 + r;
            koff[ks * 4 + tt] = row * 64 + (((4 * ks + g) ^ (row & 7)) << 3);
        }
#pragma unroll
    for (int ks2 = 0; ks2 < 2; ks2++)
#pragma unroll
        for (int cf = 0; cf < 4; cf++) {
            int row = cf * 16 + r;
            voff[ks2 * 4 + cf] = row * 64 + (((4 * ks2 + g) ^ (row & 7)) << 3);
        }
#pragma unroll
    for (int tt = 0; tt < 4; tt++)
        poffw[tt] = r * 64 + (((2 * tt + (g >> 1)) ^ (r & 7)) << 3) + (g & 1) * 4;
#pragma unroll
    for (int ks2 = 0; ks2 < 2; ks2++)
        poffr[ks2] = r * 64 + (((4 * ks2 + g) ^ (r & 7)) << 3);
    half_t* Pw = &Pl[w][0];

    // Q fragment: Q[q=r][hd = 32ks + 8g + e]  (B-operand of swapped QK^T)
    half8 qf[2];
#pragma unroll
    for (int ks = 0; ks < 2; ks++)
        qf[ks] = *(const half8*)(Qp + (size_t)(q0 + w * 16 + r) * 64 + ks * 32 + g * 8);

    f32x4 o[4] = {};          // O^T[d = 16cf + 4g + reg][q = r]
    float m = -1e30f, lsum = 0.f;

    // prologue: stage tile 0
    gl_lds16(kst, &Kl[0][0] + tid * 8);
    gl_lds16(vst, &Vl[0][0] + tid * 8);
    __syncthreads();

#define ATTN_TILE(BUF, T)                                                          \
    {                                                                              \
        if ((T) < 31) {                                                            \
            gl_lds16(kst + ((T) + 1) * 4096, &Kl[(BUF) ^ 1][0] + tid * 8);         \
            gl_lds16(vst + ((T) + 1) * 64, &Vl[(BUF) ^ 1][0] + tid * 8);           \
        }                                                                          \
        const half_t* Kc = &Kl[BUF][0];                                            \
        const half_t* Vc = &Vl[BUF][0];                                            \
        f32x4 s[4] = {};                                                           \
        _Pragma("unroll")                                                          \
        for (int ks = 0; ks < 2; ks++)                                             \
            _Pragma("unroll")                                                      \
            for (int tt = 0; tt < 4; tt++) {                                       \
                half8 kf = *(const half8*)(Kc + koff[ks * 4 + tt]);                \
                s[tt] = __builtin_amdgcn_mfma_f32_16x16x32_f16(kf, qf[ks], s[tt], 0, 0, 0); \
            }                                                                      \
        float mx = -1e30f;                                                         \
        _Pragma("unroll")                                                          \
        for (int tt = 0; tt < 4; tt++)                                             \
            mx = fmaxf(mx, fmaxf(fmaxf(s[tt][0], s[tt][1]), fmaxf(s[tt][2], s[tt][3]))); \
        mx = fmaxf(mx, __shfl_xor(mx, 16, 64));                                    \
        mx = fmaxf(mx, __shfl_xor(mx, 32, 64));                                    \
        if (!__all(mx <= m + 11.0f)) {                                             \
            float mn = fmaxf(m, mx);                                               \
            float fac = exp2_fast(m - mn);                                         \
            lsum *= fac;                                                           \
            _Pragma("unroll")                                                      \
            for (int cf = 0; cf < 4; cf++) {                                       \
                o[cf][0] *= fac; o[cf][1] *= fac; o[cf][2] *= fac; o[cf][3] *= fac; \
            }                                                                      \
            m = mn;                                                                \
        }                                                                          \
        float rs = 0.f;                                                            \
        _Pragma("unroll")                                                          \
        for (int tt = 0; tt < 4; tt++)                                             \
            _Pragma("unroll")                                                      \
            for (int e = 0; e < 4; e++) {                                          \
                float p = exp2_fast(s[tt][e] - m);                                 \
                s[tt][e] = p;                                                      \
                rs += p;                                                           \
            }                                                                      \
        rs += __shfl_xor(rs, 16, 64);                                              \
        rs += __shfl_xor(rs, 32, 64);                                              \
        lsum += rs;                                                                \
        _Pragma("unroll")                                                          \
        for (int tt = 0; tt < 4; tt++) {                                           \
            fp16x2 a = __builtin_amdgcn_cvt_pkrtz(s[tt][0], s[tt][1]);             \
            fp16x2 b = __builtin_amdgcn_cvt_pkrtz(s[tt][2], s[tt][3]);             \
            half4v v4;                                                             \
            v4[0] = (half_t)a[0]; v4[1] = (half_t)a[1];                            \
            v4[2] = (half_t)b[0]; v4[3] = (half_t)b[1];                            \
            *(half4v*)(Pw + poffw[tt]) = v4;                                       \
        }                                                                          \
        _Pragma("unroll")                                                          \
        for (int ks2 = 0; ks2 < 2; ks2++) {                                        \
            half8 pf = *(const half8*)(Pw + poffr[ks2]);                           \
            _Pragma("unroll")                                                      \
            for (int cf = 0; cf < 4; cf++) {                                       \
                half8 vf = *(const half8*)(Vc + voff[ks2 * 4 + cf]);               \
                o[cf] = __builtin_amdgcn_mfma_f32_16x16x32_f16(vf, pf, o[cf], 0, 0, 0); \
            }                                                                      \
        }                                                                          \
        __syncthreads();                                                           \
    }

    for (int t = 0; t < 32; t += 2) {
        ATTN_TILE(0, t);
        ATTN_TILE(1, t + 1);
    }

    int b = bh >> 4, h = bh & 15;
    int n = q0 + w * 16 + r;
    float inv = 1.0f / lsum;
#pragma unroll
    for (int cf = 0; cf < 4; cf++) {
        half4v ov;
#pragma unroll
        for (int reg = 0; reg < 4; reg++) ov[reg] = (half_t)(o[cf][reg] * inv);
        *(half4v*)(aoh + ((size_t)b * 2048 + n) * 1024 + h * 64 + cf * 16 + g * 4) = ov;
    }
}

// ---------------- proj GEMM: fp16, BK=64, + bias, f32 out ----------------
__global__ __launch_bounds__(256) void gemm_proj(
    const half_t* __restrict__ A, const half_t* __restrict__ Bt,
    const float* __restrict__ bias, float* __restrict__ out) {
    const int K = 1024;
    __shared__ __align__(16) half_t Al[128 * 64];
    __shared__ __align__(16) half_t Bl[128 * 64];
    int tid = threadIdx.x, w = tid >> 6, l = tid & 63;
    int wr = w >> 1, wc = w & 1, g = l >> 4, r = l & 15;
    int m0 = blockIdx.x * 128, n0 = blockIdx.y * 128;
    f32x4 acc[4][4] = {};

    for (int k0 = 0; k0 < K; k0 += 64) {
#pragma unroll
        for (int p = 0; p < 4; p++) {
            int ci = (p * 4 + w) * 64 + l;
            int row = ci >> 3, c = ci & 7;
            int lc = c ^ (row & 7);
            gl_lds16(A + (size_t)(m0 + row) * K + k0 + lc * 8, Al + (p * 4 + w) * 512);
            gl_lds16(Bt + (size_t)(n0 + row) * K + k0 + lc * 8, Bl + (p * 4 + w) * 512);
        }
        __syncthreads();
#pragma unroll
        for (int ks = 0; ks < 2; ks++) {
            half8 af[4], bf[4];
#pragma unroll
            for (int i = 0; i < 4; i++) {
                int row = wr * 64 + i * 16 + r;
                af[i] = *(const half8*)(Al + row * 64 + (((4 * ks + g) ^ (row & 7)) << 3));
                int rowb = wc * 64 + i * 16 + r;
                bf[i] = *(const half8*)(Bl + rowb * 64 + (((4 * ks + g) ^ (rowb & 7)) << 3));
            }
#pragma unroll
            for (int i = 0; i < 4; i++)
#pragma unroll
                for (int j = 0; j < 4; j++)
                    acc[i][j] = __builtin_amdgcn_mfma_f32_16x16x32_f16(af[i], bf[j], acc[i][j], 0, 0, 0);
        }
        __syncthreads();
    }

#pragma unroll
    for (int i = 0; i < 4; i++)
#pragma unroll
        for (int j = 0; j < 4; j++) {
            int gcol = n0 + wc * 64 + j * 16 + r;
            float bv = bias[gcol];
#pragma unroll
            for (int rr = 0; rr < 4; rr++) {
                int grow = m0 + wr * 64 + i * 16 + g * 4 + rr;
                out[(size_t)grow * 1024 + gcol] = acc[i][j][rr] + bv;
            }
        }
}

// ---------------- launch ----------------
extern "C" void kernel_launch(void* const* d_in, const int* in_sizes, int n_in,
                              void* d_out, int out_size, void* d_ws, size_t ws_size,
                              hipStream_t stream) {
    const float* x = (const float*)d_in[0];
    const float* Wqkv = (const float*)d_in[1];
    const float* Wproj = (const float*)d_in[2];
    const float* bproj = (const float*)d_in[3];
    const float* qscale = (const float*)d_in[4];
    const float* kscale = (const float*)d_in[5];
    float* out = (float*)d_out;

    char* ws = (char*)d_ws;
    half_t* xh  = (half_t*)(ws + 0);         //  8.0 MB (4096 x 1024 fp16)
    half_t* wqt = (half_t*)(ws + 8388608);   //  6.0 MB (3072 x 1024 fp16, transposed)
    half_t* wpt = (half_t*)(ws + 14680064);  //  2.0 MB (1024 x 1024 fp16, transposed)
    half_t* qh  = (half_t*)(ws + 16777216);  //  8.0 MB (b,h,n,f)
    half_t* kh  = (half_t*)(ws + 25165824);  //  8.0 MB (b,h,n,f)
    half_t* vth = (half_t*)(ws + 33554432);  //  8.0 MB (b,h,f,n)
    half_t* aoh = (half_t*)(ws + 41943040);  //  8.0 MB (b,n,c)

    prep_x<<<4096, 256, 0, stream>>>(x, xh, 4194304);
    prep_wqkv<<<dim3(96, 32), dim3(32, 8), 0, stream>>>(Wqkv, wqt);
    prep_wproj<<<dim3(32, 32), dim3(32, 8), 0, stream>>>(Wproj, wpt);
    gemm_qkv<<<dim3(32, 24), 256, 0, stream>>>(xh, wqt, qscale, kscale, qh, kh, vth);
    attn<<<dim3(16, 32), 512, 0, stream>>>(qh, kh, vth, aoh);
    gemm_proj<<<dim3(32, 8), 256, 0, stream>>>(aoh, wpt, bproj, out);
}

// Round 7
// 131.355 us; speedup vs baseline: 1.8753x; 1.0533x over previous
//
#include <hip/hip_runtime.h>

// Problem constants: B=2, N=2048, C=1024, H=16, hd=64
// x:(2,2048,1024) f32; Wqkv:(1024,3072); Wproj:(1024,1024); bproj:(1024); q_scale,k_scale:(64)
// out:(2,2048,1024) f32

typedef _Float16 half_t;
typedef __attribute__((ext_vector_type(2))) __fp16 fp16x2;
typedef __attribute__((ext_vector_type(4))) _Float16 half4v;
typedef __attribute__((ext_vector_type(8))) _Float16 half8;
typedef __attribute__((ext_vector_type(4))) float f32x4;

#define DI __device__ __forceinline__

DI void gl_lds16(const void* g, void* l) {
    __builtin_amdgcn_global_load_lds((const __attribute__((address_space(1))) void*)g,
                                     (__attribute__((address_space(3))) void*)l, 16, 0, 0);
}

DI float exp2_fast(float x) {
    float r;
    asm("v_exp_f32 %0, %1" : "=v"(r) : "v"(x));
    return r;
}

// ---------------- merged prep kernel ----------------
// blocks [0,4096): x f32->fp16 ; [4096,7168): Wqkv transpose->fp16 ; [7168,8192): Wproj
__global__ void prep_all(const float* __restrict__ x, const float* __restrict__ Wqkv,
                         const float* __restrict__ Wproj, half_t* __restrict__ xh,
                         half_t* __restrict__ wqt, half_t* __restrict__ wpt) {
    __shared__ float t[32][33];
    int bid = blockIdx.x;
    if (bid < 4096) {
        int i = (bid * 256 + threadIdx.x) * 4;
        float4 v = *(const float4*)(x + i);
        half4v o;
        o[0] = (half_t)v.x; o[1] = (half_t)v.y; o[2] = (half_t)v.z; o[3] = (half_t)v.w;
        *(half4v*)(xh + i) = o;
    } else if (bid < 4096 + 3072) {
        int i = bid - 4096;
        int c0 = (i % 96) * 32, r0 = (i / 96) * 32;
        int tx = threadIdx.x & 31, ty = threadIdx.x >> 5;
#pragma unroll
        for (int k = 0; k < 4; k++)
            t[ty + 8 * k][tx] = Wqkv[(size_t)(r0 + ty + 8 * k) * 3072 + c0 + tx];
        __syncthreads();
#pragma unroll
        for (int k = 0; k < 4; k++)
            wqt[(size_t)(c0 + ty + 8 * k) * 1024 + r0 + tx] = (half_t)t[tx][ty + 8 * k];
    } else {
        int i = bid - 4096 - 3072;
        int c0 = (i % 32) * 32, r0 = (i / 32) * 32;
        int tx = threadIdx.x & 31, ty = threadIdx.x >> 5;
#pragma unroll
        for (int k = 0; k < 4; k++)
            t[ty + 8 * k][tx] = Wproj[(size_t)(r0 + ty + 8 * k) * 1024 + c0 + tx];
        __syncthreads();
#pragma unroll
        for (int k = 0; k < 4; k++)
            wpt[(size_t)(c0 + ty + 8 * k) * 1024 + r0 + tx] = (half_t)t[tx][ty + 8 * k];
    }
}

// ---------------- QKV GEMM: fp16, BK=64, dbuf LDS, fused RMSNorm epilogue ----------------
// C[4096][3072] = x[4096][1024] @ Wqkv. Each block's 128-col span lies in exactly one of
// {q,k,v} (1024 % 128 == 0). q/k epilogue: RMSNorm over hd=64 from f32 acc (4-step shfl
// reduce over the 16-lane r-group), fold q_scale/k_scale and (hd^-0.5 * log2e) into q.
// v epilogue: store transposed (b,h,f,n).
__global__ __launch_bounds__(256) void gemm_qkv(
    const half_t* __restrict__ A, const half_t* __restrict__ Bt,
    const float* __restrict__ qs, const float* __restrict__ ks,
    half_t* __restrict__ qh, half_t* __restrict__ kh, half_t* __restrict__ vth) {
    const int K = 1024;
    __shared__ __align__(16) half_t Al[2][128 * 64];
    __shared__ __align__(16) half_t Bl[2][128 * 64];
    int tid = threadIdx.x;
    int w = tid >> 6, l = tid & 63;
    int wr = w >> 1, wc = w & 1;
    int g = l >> 4, r = l & 15;
    int m0 = blockIdx.x * 128, n0 = blockIdx.y * 128;
    f32x4 acc[4][4] = {};

#define STAGE_QKV(kt, buf)                                                        \
    {                                                                             \
        _Pragma("unroll")                                                         \
        for (int p = 0; p < 4; p++) {                                             \
            int ci = p * 256 + tid;                                               \
            int row = ci >> 3, c = ci & 7, lc = c ^ (row & 7);                    \
            gl_lds16(A + (size_t)(m0 + row) * K + (kt) * 64 + lc * 8,             \
                     &Al[buf][0] + ci * 8);                                       \
            gl_lds16(Bt + (size_t)(n0 + row) * K + (kt) * 64 + lc * 8,            \
                     &Bl[buf][0] + ci * 8);                                       \
        }                                                                         \
    }

    STAGE_QKV(0, 0);
    __syncthreads();
    int cur = 0;
    for (int kt = 0; kt < 16; kt++) {
        if (kt < 15) STAGE_QKV(kt + 1, cur ^ 1);
#pragma unroll
        for (int ks2 = 0; ks2 < 2; ks2++) {
            half8 af[4], bf[4];
#pragma unroll
            for (int i = 0; i < 4; i++) {
                int row = wr * 64 + i * 16 + r;
                af[i] = *(const half8*)(&Al[cur][0] + row * 64 + (((4 * ks2 + g) ^ (row & 7)) << 3));
                int rowb = wc * 64 + i * 16 + r;
                bf[i] = *(const half8*)(&Bl[cur][0] + rowb * 64 + (((4 * ks2 + g) ^ (rowb & 7)) << 3));
            }
#pragma unroll
            for (int i = 0; i < 4; i++)
#pragma unroll
                for (int j = 0; j < 4; j++)
                    acc[i][j] = __builtin_amdgcn_mfma_f32_16x16x32_f16(af[i], bf[j], acc[i][j], 0, 0, 0);
        }
        __syncthreads();
        cur ^= 1;
    }

    int tsec = n0 >> 10;  // 0=q, 1=k, 2=v (uniform per block)
    if (tsec == 2) {
#pragma unroll
        for (int i = 0; i < 4; i++)
#pragma unroll
            for (int j = 0; j < 4; j++) {
                int gcol = n0 + wc * 64 + j * 16 + r;
                int h = (gcol >> 6) & 15;
                int f = gcol & 63;
                int growb = m0 + wr * 64 + i * 16 + g * 4;
                int b = growb >> 11;
                int n = growb & 2047;
                half4v pv;
#pragma unroll
                for (int rr = 0; rr < 4; rr++) pv[rr] = (half_t)acc[i][j][rr];
                *(half4v*)(vth + ((size_t)(b * 16 + h) * 64 + f) * 2048 + n) = pv;
            }
    } else {
        const float* sc = (tsec == 0) ? qs : ks;
        half_t* dst = (tsec == 0) ? qh : kh;
        float extra = (tsec == 0) ? (0.125f * 1.44269504f) : 1.0f;  // fold hd^-0.5*log2e into q
        float scv[4];
#pragma unroll
        for (int j = 0; j < 4; j++) scv[j] = sc[j * 16 + r];
#pragma unroll
        for (int i = 0; i < 4; i++)
#pragma unroll
            for (int rr = 0; rr < 4; rr++) {
                float ss = 0.f;
#pragma unroll
                for (int j = 0; j < 4; j++) ss += acc[i][j][rr] * acc[i][j][rr];
#pragma unroll
                for (int d = 1; d < 16; d <<= 1) ss += __shfl_xor(ss, d, 64);
                float inv = extra / (sqrtf(ss) * 0.125f + 1e-8f);  // rms = ||row||/8
                int grow = m0 + wr * 64 + i * 16 + g * 4 + rr;
                int b = grow >> 11;
                int n = grow & 2047;
#pragma unroll
                for (int j = 0; j < 4; j++) {
                    int gcol = n0 + wc * 64 + j * 16 + r;
                    int h = (gcol >> 6) & 15;
                    int f = gcol & 63;
                    dst[((size_t)(b * 16 + h) * 2048 + n) * 64 + f] =
                        (half_t)(acc[i][j][rr] * inv * scv[j]);
                }
            }
    }
}

// ---------------- flash attention, swapped-QK in-register softmax (defer-max) --------
// grid (16 q-tiles, 32 bh). Block: 512 thr = 8 waves, each wave 16 q-rows (1 q/lane).
// S^T = mfma(K_frag, Q_frag): lane holds S^T[kv=16tt+4g+reg][q=r], log2 units.
// Defer-max (THR=11): P = exp2(s - m) <= 2^11, fp16-safe (PROVEN R5 numerics; the
// no-max variant failed at 4.7e-2 — do not remove max tracking).
// lsum kept per-lane (fac is g-uniform); single cross-lane reduce in epilogue.
// PV as O^T = mfma(V^T_frag, P^T_frag); P repacked via per-wave swizzled LDS.
__global__ __launch_bounds__(512, 4) void attn(
    const half_t* __restrict__ qh, const half_t* __restrict__ kh,
    const half_t* __restrict__ vth, half_t* __restrict__ aoh) {
    int bh = blockIdx.y;
    int q0 = blockIdx.x * 128;
    const half_t* Qp = qh + (size_t)bh * 2048 * 64;
    const half_t* Kp = kh + (size_t)bh * 2048 * 64;
    const half_t* Vp = vth + (size_t)bh * 64 * 2048;  // (feat, n)
    __shared__ __align__(16) half_t Kl[2][64 * 64];
    __shared__ __align__(16) half_t Vl[2][64 * 64];   // [feat][kv]
    __shared__ __align__(16) half_t Pl[8][16 * 64];   // per-wave: 16 q x 64 kv (chunk-swizzled)
    int tid = threadIdx.x, w = tid >> 6, l = tid & 63, g = l >> 4, r = l & 15;

    // staging coords: 512 chunks of 16B per 64x64 fp16 buffer
    int srow = tid >> 3, sc = tid & 7, slc = sc ^ (srow & 7);
    const half_t* kst = Kp + (size_t)srow * 64 + slc * 8;
    const half_t* vst = Vp + (size_t)srow * 2048 + slc * 8;

    // hoisted LDS element-offsets (loop-invariant)
    int koff[8], voff[8], poffw[4], poffr[2];
#pragma unroll
    for (int ks = 0; ks < 2; ks++)
#pragma unroll
        for (int tt = 0; tt < 4; tt++) {
            int row = tt * 16 + r;
            koff[ks * 4 + tt] = row * 64 + (((4 * ks + g) ^ (row & 7)) << 3);
        }
#pragma unroll
    for (int ks2 = 0; ks2 < 2; ks2++)
#pragma unroll
        for (int cf = 0; cf < 4; cf++) {
            int row = cf * 16 + r;
            voff[ks2 * 4 + cf] = row * 64 + (((4 * ks2 + g) ^ (row & 7)) << 3);
        }
#pragma unroll
    for (int tt = 0; tt < 4; tt++)
        poffw[tt] = r * 64 + (((2 * tt + (g >> 1)) ^ (r & 7)) << 3) + (g & 1) * 4;
#pragma unroll
    for (int ks2 = 0; ks2 < 2; ks2++)
        poffr[ks2] = r * 64 + (((4 * ks2 + g) ^ (r & 7)) << 3);
    half_t* Pw = &Pl[w][0];

    // Q fragment: Q[q=r][hd = 32ks + 8g + e]  (B-operand of swapped QK^T)
    half8 qf[2];
#pragma unroll
    for (int ks = 0; ks < 2; ks++)
        qf[ks] = *(const half8*)(Qp + (size_t)(q0 + w * 16 + r) * 64 + ks * 32 + g * 8);

    f32x4 o[4] = {};          // O^T[d = 16cf + 4g + reg][q = r]
    float m = -1e30f, lsum = 0.f;  // lsum: per-lane partial, reduced in epilogue

    // prologue: stage tile 0
    gl_lds16(kst, &Kl[0][0] + tid * 8);
    gl_lds16(vst, &Vl[0][0] + tid * 8);
    __syncthreads();

#define ATTN_TILE(BUF, T)                                                          \
    {                                                                              \
        if ((T) < 31) {                                                            \
            gl_lds16(kst + ((T) + 1) * 4096, &Kl[(BUF) ^ 1][0] + tid * 8);         \
            gl_lds16(vst + ((T) + 1) * 64, &Vl[(BUF) ^ 1][0] + tid * 8);           \
        }                                                                          \
        const half_t* Kc = &Kl[BUF][0];                                            \
        const half_t* Vc = &Vl[BUF][0];                                            \
        f32x4 s[4] = {};                                                           \
        _Pragma("unroll")                                                          \
        for (int ks = 0; ks < 2; ks++)                                             \
            _Pragma("unroll")                                                      \
            for (int tt = 0; tt < 4; tt++) {                                       \
                half8 kf = *(const half8*)(Kc + koff[ks * 4 + tt]);                \
                s[tt] = __builtin_amdgcn_mfma_f32_16x16x32_f16(kf, qf[ks], s[tt], 0, 0, 0); \
            }                                                                      \
        float mx = -1e30f;                                                         \
        _Pragma("unroll")                                                          \
        for (int tt = 0; tt < 4; tt++)                                             \
            mx = fmaxf(mx, fmaxf(fmaxf(s[tt][0], s[tt][1]), fmaxf(s[tt][2], s[tt][3]))); \
        mx = fmaxf(mx, __shfl_xor(mx, 16, 64));                                    \
        mx = fmaxf(mx, __shfl_xor(mx, 32, 64));                                    \
        if (!__all(mx <= m + 11.0f)) {                                             \
            float mn = fmaxf(m, mx);                                               \
            float fac = exp2_fast(m - mn);                                         \
            lsum *= fac;                                                           \
            _Pragma("unroll")                                                      \
            for (int cf = 0; cf < 4; cf++) {                                       \
                o[cf][0] *= fac; o[cf][1] *= fac; o[cf][2] *= fac; o[cf][3] *= fac; \
            }                                                                      \
            m = mn;                                                                \
        }                                                                          \
        _Pragma("unroll")                                                          \
        for (int tt = 0; tt < 4; tt++)                                             \
            _Pragma("unroll")                                                      \
            for (int e = 0; e < 4; e++) {                                          \
                float p = exp2_fast(s[tt][e] - m);                                 \
                s[tt][e] = p;                                                      \
                lsum += p;                                                         \
            }                                                                      \
        _Pragma("unroll")                                                          \
        for (int tt = 0; tt < 4; tt++) {                                           \
            fp16x2 a = __builtin_amdgcn_cvt_pkrtz(s[tt][0], s[tt][1]);             \
            fp16x2 b = __builtin_amdgcn_cvt_pkrtz(s[tt][2], s[tt][3]);             \
            half4v v4;                                                             \
            v4[0] = (half_t)a[0]; v4[1] = (half_t)a[1];                            \
            v4[2] = (half_t)b[0]; v4[3] = (half_t)b[1];                            \
            *(half4v*)(Pw + poffw[tt]) = v4;                                       \
        }                                                                          \
        _Pragma("unroll")                                                          \
        for (int ks2 = 0; ks2 < 2; ks2++) {                                        \
            half8 pf = *(const half8*)(Pw + poffr[ks2]);                           \
            _Pragma("unroll")                                                      \
            for (int cf = 0; cf < 4; cf++) {                                       \
                half8 vf = *(const half8*)(Vc + voff[ks2 * 4 + cf]);               \
                o[cf] = __builtin_amdgcn_mfma_f32_16x16x32_f16(vf, pf, o[cf], 0, 0, 0); \
            }                                                                      \
        }                                                                          \
        __syncthreads();                                                           \
    }

    for (int t = 0; t < 32; t += 2) {
        ATTN_TILE(0, t);
        ATTN_TILE(1, t + 1);
    }

    // cross-lane (g-group) sum: lanes r, r+16, r+32, r+48 hold disjoint kv-slots
    lsum += __shfl_xor(lsum, 16, 64);
    lsum += __shfl_xor(lsum, 32, 64);

    int b = bh >> 4, h = bh & 15;
    int n = q0 + w * 16 + r;
    float inv = 1.0f / lsum;
#pragma unroll
    for (int cf = 0; cf < 4; cf++) {
        half4v ov;
#pragma unroll
        for (int reg = 0; reg < 4; reg++) ov[reg] = (half_t)(o[cf][reg] * inv);
        *(half4v*)(aoh + ((size_t)b * 2048 + n) * 1024 + h * 64 + cf * 16 + g * 4) = ov;
    }
}

// ---------------- proj GEMM: fp16, BK=64, + bias, f32 out ----------------
__global__ __launch_bounds__(256) void gemm_proj(
    const half_t* __restrict__ A, const half_t* __restrict__ Bt,
    const float* __restrict__ bias, float* __restrict__ out) {
    const int K = 1024;
    __shared__ __align__(16) half_t Al[128 * 64];
    __shared__ __align__(16) half_t Bl[128 * 64];
    int tid = threadIdx.x, w = tid >> 6, l = tid & 63;
    int wr = w >> 1, wc = w & 1, g = l >> 4, r = l & 15;
    int m0 = blockIdx.x * 128, n0 = blockIdx.y * 128;
    f32x4 acc[4][4] = {};

    for (int k0 = 0; k0 < K; k0 += 64) {
#pragma unroll
        for (int p = 0; p < 4; p++) {
            int ci = (p * 4 + w) * 64 + l;
            int row = ci >> 3, c = ci & 7;
            int lc = c ^ (row & 7);
            gl_lds16(A + (size_t)(m0 + row) * K + k0 + lc * 8, Al + (p * 4 + w) * 512);
            gl_lds16(Bt + (size_t)(n0 + row) * K + k0 + lc * 8, Bl + (p * 4 + w) * 512);
        }
        __syncthreads();
#pragma unroll
        for (int ks = 0; ks < 2; ks++) {
            half8 af[4], bf[4];
#pragma unroll
            for (int i = 0; i < 4; i++) {
                int row = wr * 64 + i * 16 + r;
                af[i] = *(const half8*)(Al + row * 64 + (((4 * ks + g) ^ (row & 7)) << 3));
                int rowb = wc * 64 + i * 16 + r;
                bf[i] = *(const half8*)(Bl + rowb * 64 + (((4 * ks + g) ^ (rowb & 7)) << 3));
            }
#pragma unroll
            for (int i = 0; i < 4; i++)
#pragma unroll
                for (int j = 0; j < 4; j++)
                    acc[i][j] = __builtin_amdgcn_mfma_f32_16x16x32_f16(af[i], bf[j], acc[i][j], 0, 0, 0);
        }
        __syncthreads();
    }

#pragma unroll
    for (int i = 0; i < 4; i++)
#pragma unroll
        for (int j = 0; j < 4; j++) {
            int gcol = n0 + wc * 64 + j * 16 + r;
            float bv = bias[gcol];
#pragma unroll
            for (int rr = 0; rr < 4; rr++) {
                int grow = m0 + wr * 64 + i * 16 + g * 4 + rr;
                out[(size_t)grow * 1024 + gcol] = acc[i][j][rr] + bv;
            }
        }
}

// ---------------- launch ----------------
extern "C" void kernel_launch(void* const* d_in, const int* in_sizes, int n_in,
                              void* d_out, int out_size, void* d_ws, size_t ws_size,
                              hipStream_t stream) {
    const float* x = (const float*)d_in[0];
    const float* Wqkv = (const float*)d_in[1];
    const float* Wproj = (const float*)d_in[2];
    const float* bproj = (const float*)d_in[3];
    const float* qscale = (const float*)d_in[4];
    const float* kscale = (const float*)d_in[5];
    float* out = (float*)d_out;

    char* ws = (char*)d_ws;
    half_t* xh  = (half_t*)(ws + 0);         //  8.0 MB (4096 x 1024 fp16)
    half_t* wqt = (half_t*)(ws + 8388608);   //  6.0 MB (3072 x 1024 fp16, transposed)
    half_t* wpt = (half_t*)(ws + 14680064);  //  2.0 MB (1024 x 1024 fp16, transposed)
    half_t* qh  = (half_t*)(ws + 16777216);  //  8.0 MB (b,h,n,f)
    half_t* kh  = (half_t*)(ws + 25165824);  //  8.0 MB (b,h,n,f)
    half_t* vth = (half_t*)(ws + 33554432);  //  8.0 MB (b,h,f,n)
    half_t* aoh = (half_t*)(ws + 41943040);  //  8.0 MB (b,n,c)

    prep_all<<<8192, 256, 0, stream>>>(x, Wqkv, Wproj, xh, wqt, wpt);
    gemm_qkv<<<dim3(32, 24), 256, 0, stream>>>(xh, wqt, qscale, kscale, qh, kh, vth);
    attn<<<dim3(16, 32), 512, 0, stream>>>(qh, kh, vth, aoh);
    gemm_proj<<<dim3(32, 8), 256, 0, stream>>>(aoh, wpt, bproj, out);
}